// Round 2
// baseline (5746.435 us; speedup 1.0000x reference)
//
#include <hip/hip_runtime.h>

#define N_NODES  100000
#define N_EDGES  3200000
#define NFEAT    256
#define NHID     128
#define NCLASS   16
#define TEXT_CNT 50000

#define RPB      256                          // rows per bucket
#define NB       ((N_NODES + RPB - 1) / RPB)  // 391 buckets
#define A_EPT    16                           // edges/thread, count pass
#define S_EPT    32                           // edges/thread, scatter pass

// ---------------- bucket count (LDS-aggregated histogram) ----------------

__global__ __launch_bounds__(256) void bucket_count_kernel(const int* __restrict__ rows,
                                                           int* __restrict__ gcount, int E) {
  __shared__ int hist[NB];
  for (int i = threadIdx.x; i < NB; i += 256) hist[i] = 0;
  __syncthreads();
  int base = blockIdx.x * (256 * A_EPT);
#pragma unroll
  for (int i = 0; i < A_EPT; ++i) {
    int e = base + i * 256 + threadIdx.x;
    if (e < E) atomicAdd(&hist[rows[e] >> 8], 1);
  }
  __syncthreads();
  for (int i = threadIdx.x; i < NB; i += 256) {
    int v = hist[i];
    if (v) atomicAdd(&gcount[i], v);
  }
}

// ---------------- scan bucket counts -> bases + cursors ----------------

__global__ __launch_bounds__(512) void bucket_scan_kernel(const int* __restrict__ gcount,
                                                          int* __restrict__ bbase,
                                                          int* __restrict__ gcursor) {
  __shared__ int s[512];
  int t = threadIdx.x;
  int v = (t < NB) ? gcount[t] : 0;
  s[t] = v;
  __syncthreads();
  for (int off = 1; off < 512; off <<= 1) {
    int u = (t >= off) ? s[t - off] : 0;
    __syncthreads();
    s[t] += u;
    __syncthreads();
  }
  if (t < NB) {
    int ex = s[t] - v;
    bbase[t] = ex;
    gcursor[t] = ex;
  }
  if (t == 0) bbase[NB] = N_EDGES;
}

// ---------------- multi-split scatter: edges -> packed buckets ----------------
// packed[p] = { (rowlocal<<17) | col , float_bits(val) }

__global__ __launch_bounds__(256) void bucket_scatter_kernel(const int* __restrict__ rows,
                                                             const int* __restrict__ cols,
                                                             const float* __restrict__ vals,
                                                             int* __restrict__ gcursor,
                                                             int2* __restrict__ packed, int E) {
  __shared__ int hist[NB];
  __shared__ int cur[NB];
  for (int i = threadIdx.x; i < NB; i += 256) hist[i] = 0;
  __syncthreads();
  int base = blockIdx.x * (256 * S_EPT);
#pragma unroll
  for (int i = 0; i < S_EPT; ++i) {
    int e = base + i * 256 + threadIdx.x;
    if (e < E) atomicAdd(&hist[rows[e] >> 8], 1);
  }
  __syncthreads();
  for (int i = threadIdx.x; i < NB; i += 256) {
    int h = hist[i];
    cur[i] = h ? atomicAdd(&gcursor[i], h) : 0;
  }
  __syncthreads();
#pragma unroll
  for (int i = 0; i < S_EPT; ++i) {
    int e = base + i * 256 + threadIdx.x;
    if (e < E) {
      int r = rows[e];
      int b = r >> 8;
      int p = atomicAdd(&cur[b], 1);
      packed[p] = make_int2(((r & 255) << 17) | cols[e], __float_as_int(vals[e]));
    }
  }
}

// ---------------- bucketed SpMM with LDS accumulation ----------------
// One block per bucket. acc[256][128] fp32 in LDS (128 KB). Wave per edge.

__global__ __launch_bounds__(512) void spmm_bucket_kernel(const int* __restrict__ bbase,
                                                          const int2* __restrict__ packed,
                                                          const float* __restrict__ src,
                                                          float* __restrict__ dst,
                                                          const float* __restrict__ bias,
                                                          int relu) {
  __shared__ __align__(16) float acc[RPB][NHID];
  float4* accv = (float4*)acc;
  for (int i = threadIdx.x; i < RPB * NHID / 4; i += 512)
    accv[i] = make_float4(0.f, 0.f, 0.f, 0.f);
  __syncthreads();

  int b = blockIdx.x;
  int s = bbase[b], e = bbase[b + 1];
  int w = threadIdx.x >> 6;
  int lane = threadIdx.x & 63;
  const float2* src2 = (const float2*)src;

  int i = s + w;
  // unroll x4 (stride 8 waves) to keep 4 gathers in flight per wave
  for (; i + 24 < e; i += 32) {
    int2 p0 = packed[i];
    int2 p1 = packed[i + 8];
    int2 p2 = packed[i + 16];
    int2 p3 = packed[i + 24];
    float2 g0 = src2[(size_t)(p0.x & 0x1FFFF) * 64 + lane];
    float2 g1 = src2[(size_t)(p1.x & 0x1FFFF) * 64 + lane];
    float2 g2 = src2[(size_t)(p2.x & 0x1FFFF) * 64 + lane];
    float2 g3 = src2[(size_t)(p3.x & 0x1FFFF) * 64 + lane];
    float v0 = __int_as_float(p0.y), v1 = __int_as_float(p1.y);
    float v2 = __int_as_float(p2.y), v3 = __int_as_float(p3.y);
    int r0 = p0.x >> 17, r1 = p1.x >> 17, r2 = p2.x >> 17, r3 = p3.x >> 17;
    atomicAdd(&acc[r0][2 * lane], v0 * g0.x);
    atomicAdd(&acc[r0][2 * lane + 1], v0 * g0.y);
    atomicAdd(&acc[r1][2 * lane], v1 * g1.x);
    atomicAdd(&acc[r1][2 * lane + 1], v1 * g1.y);
    atomicAdd(&acc[r2][2 * lane], v2 * g2.x);
    atomicAdd(&acc[r2][2 * lane + 1], v2 * g2.y);
    atomicAdd(&acc[r3][2 * lane], v3 * g3.x);
    atomicAdd(&acc[r3][2 * lane + 1], v3 * g3.y);
  }
  for (; i < e; i += 8) {
    int2 pk = packed[i];
    int col = pk.x & 0x1FFFF;
    int rl = pk.x >> 17;
    float v = __int_as_float(pk.y);
    float2 g = src2[(size_t)col * 64 + lane];
    atomicAdd(&acc[rl][2 * lane], v * g.x);
    atomicAdd(&acc[rl][2 * lane + 1], v * g.y);
  }
  __syncthreads();

  int row0 = b * RPB;
  int nrow = min(RPB, N_NODES - row0);
  for (int idx = threadIdx.x; idx < nrow * (NHID / 4); idx += 512) {
    int r = idx >> 5;
    int q = idx & 31;
    float4 a = accv[r * 32 + q];
    if (bias) {
      a.x += bias[q * 4 + 0];
      a.y += bias[q * 4 + 1];
      a.z += bias[q * 4 + 2];
      a.w += bias[q * 4 + 3];
    }
    if (relu) {
      a.x = fmaxf(a.x, 0.f); a.y = fmaxf(a.y, 0.f);
      a.z = fmaxf(a.z, 0.f); a.w = fmaxf(a.w, 0.f);
    }
    *(float4*)&dst[(size_t)(row0 + r) * NHID + q * 4] = a;
  }
}

// ---------------- FP32 tiled GEMM: C[M,N] = A[M,K] @ B[K,N] (+bias) ----------------
// BM=128, BN=128, BK=16, 256 threads, 8x8 per thread.

__global__ __launch_bounds__(256) void gemm_kernel(const float* __restrict__ A,
                                                   const float* __restrict__ B,
                                                   const float* __restrict__ bias,
                                                   float* __restrict__ C,
                                                   int M, int K, int N) {
  __shared__ float As[16][132];
  __shared__ float Bs[16][132];
  int tid = threadIdx.x;
  int tx = tid & 15;
  int ty = tid >> 4;
  int brow = blockIdx.x * 128;
  int bcol = blockIdx.y * 128;

  float acc[8][8];
#pragma unroll
  for (int i = 0; i < 8; ++i)
#pragma unroll
    for (int j = 0; j < 8; ++j) acc[i][j] = 0.f;

  for (int k0 = 0; k0 < K; k0 += 16) {
#pragma unroll
    for (int li = 0; li < 2; ++li) {
      int idx = tid + li * 256;
      int r = idx >> 2;
      int kq = (idx & 3) << 2;
      int gr = brow + r;
      float4 v = make_float4(0.f, 0.f, 0.f, 0.f);
      if (gr < M) v = *(const float4*)&A[(size_t)gr * K + k0 + kq];
      As[kq + 0][r] = v.x;
      As[kq + 1][r] = v.y;
      As[kq + 2][r] = v.z;
      As[kq + 3][r] = v.w;
    }
#pragma unroll
    for (int li = 0; li < 2; ++li) {
      int idx = tid + li * 256;
      int kk = idx >> 5;
      int nq = (idx & 31) << 2;
      float4 v = *(const float4*)&B[(size_t)(k0 + kk) * N + bcol + nq];
      *(float4*)&Bs[kk][nq] = v;
    }
    __syncthreads();

#pragma unroll
    for (int kk = 0; kk < 16; ++kk) {
      float a[8], b[8];
      *(float4*)&a[0] = *(float4*)&As[kk][ty * 8];
      *(float4*)&a[4] = *(float4*)&As[kk][ty * 8 + 4];
      *(float4*)&b[0] = *(float4*)&Bs[kk][tx * 8];
      *(float4*)&b[4] = *(float4*)&Bs[kk][tx * 8 + 4];
#pragma unroll
      for (int i = 0; i < 8; ++i)
#pragma unroll
        for (int j = 0; j < 8; ++j) acc[i][j] += a[i] * b[j];
    }
    __syncthreads();
  }

  float bv[8];
#pragma unroll
  for (int j = 0; j < 8; ++j)
    bv[j] = bias ? bias[bcol + tx * 8 + j] : 0.f;

#pragma unroll
  for (int i = 0; i < 8; ++i) {
    int row = brow + ty * 8 + i;
    if (row < M) {
      float4 o0, o1;
      o0.x = acc[i][0] + bv[0]; o0.y = acc[i][1] + bv[1];
      o0.z = acc[i][2] + bv[2]; o0.w = acc[i][3] + bv[3];
      o1.x = acc[i][4] + bv[4]; o1.y = acc[i][5] + bv[5];
      o1.z = acc[i][6] + bv[6]; o1.w = acc[i][7] + bv[7];
      *(float4*)&C[(size_t)row * N + bcol + tx * 8] = o0;
      *(float4*)&C[(size_t)row * N + bcol + tx * 8 + 4] = o1;
    }
  }
}

// ---------------- fold classifier weights: Wc = W2 @ cW, bc = cb + b2 @ cW ----------------

__global__ __launch_bounds__(256) void wc_kernel(const float* __restrict__ W2,
                                                 const float* __restrict__ b2,
                                                 const float* __restrict__ cW1,
                                                 const float* __restrict__ cb1,
                                                 const float* __restrict__ cW2,
                                                 const float* __restrict__ cb2,
                                                 float* __restrict__ Wc1, float* __restrict__ bc1,
                                                 float* __restrict__ Wc2, float* __restrict__ bc2) {
  int idx = blockIdx.x * 256 + threadIdx.x;   // 0..4095
  int set = idx >> 11;
  int e = idx & 2047;
  int i = e >> 4;
  int c = e & 15;
  const float* cw = set ? cW2 : cW1;
  float acc = 0.f;
  for (int k = 0; k < NFEAT; ++k)
    acc += W2[(size_t)i * NFEAT + k] * cw[k * NCLASS + c];
  (set ? Wc2 : Wc1)[e] = acc;
  if (idx < 32) {
    int s2 = idx >> 4, c2 = idx & 15;
    const float* cwb = s2 ? cW2 : cW1;
    float b = (s2 ? cb2 : cb1)[c2];
    for (int k = 0; k < NFEAT; ++k) b += b2[k] * cwb[k * NCLASS + c2];
    (s2 ? bc2 : bc1)[c2] = b;
  }
}

// ---------------- classifier: cls[r,:] = t3[row0+r,:] @ Wc + bc ----------------

__global__ __launch_bounds__(256) void cls_kernel(const float* __restrict__ t3,
                                                  const float* __restrict__ Wc,
                                                  const float* __restrict__ bc,
                                                  float* __restrict__ outp,
                                                  int row0, int nrows) {
  int lane = threadIdx.x & 63;
  int wav = blockIdx.x * 4 + (threadIdx.x >> 6);
  int nw = gridDim.x * 4;
  int c = lane & 15;
  int kg = lane >> 4;
  float w[32];
#pragma unroll
  for (int j = 0; j < 32; ++j) w[j] = Wc[(kg * 32 + j) * NCLASS + c];
  float bcv = bc[c];
  for (int r = wav; r < nrows; r += nw) {
    const float4* rowp = (const float4*)&t3[(size_t)(row0 + r) * NHID + kg * 32];
    float acc = 0.f;
#pragma unroll
    for (int q = 0; q < 8; ++q) {
      float4 d = rowp[q];
      acc += d.x * w[q * 4 + 0] + d.y * w[q * 4 + 1] + d.z * w[q * 4 + 2] + d.w * w[q * 4 + 3];
    }
    acc += __shfl_xor(acc, 16);
    acc += __shfl_xor(acc, 32);
    if (lane < 16) outp[(size_t)r * NCLASS + lane] = acc + bcv;
  }
}

// ---------------- launch ----------------

extern "C" void kernel_launch(void* const* d_in, const int* in_sizes, int n_in,
                              void* d_out, int out_size, void* d_ws, size_t ws_size,
                              hipStream_t stream) {
  const float* x     = (const float*)d_in[0];
  const int*   arows = (const int*)d_in[1];
  const int*   acols = (const int*)d_in[2];
  const float* avals = (const float*)d_in[3];
  const float* W1    = (const float*)d_in[4];
  const float* b1    = (const float*)d_in[5];
  const float* W2    = (const float*)d_in[6];
  const float* b2    = (const float*)d_in[7];
  const float* cW1   = (const float*)d_in[8];
  const float* cb1   = (const float*)d_in[9];
  const float* cW2   = (const float*)d_in[10];
  const float* cb2   = (const float*)d_in[11];
  float* outp = (float*)d_out;

  char* ws = (char*)d_ws;
  size_t off = 0;
  auto alloc = [&](size_t bytes) -> void* {
    void* p = ws + off;
    off += (bytes + 255) & ~(size_t)255;
    return p;
  };
  float* B1      = (float*)alloc((size_t)N_NODES * NHID * 4);   // t1 / t3
  float* B2      = (float*)alloc((size_t)N_NODES * NHID * 4);   // h
  int2*  packed  = (int2*) alloc((size_t)N_EDGES * 8);
  int*   gcount  = (int*)  alloc((size_t)NB * 4);
  int*   bbase   = (int*)  alloc((size_t)(NB + 1) * 4);
  int*   gcursor = (int*)  alloc((size_t)NB * 4);
  float* Wc1     = (float*)alloc(NHID * NCLASS * 4);
  float* Wc2     = (float*)alloc(NHID * NCLASS * 4);
  float* bc1     = (float*)alloc(64);
  float* bc2     = (float*)alloc(64);

  // ---- bucket build ----
  hipMemsetAsync(gcount, 0, (size_t)NB * 4, stream);
  int nblkA = (N_EDGES + 256 * A_EPT - 1) / (256 * A_EPT);   // 782
  bucket_count_kernel<<<nblkA, 256, 0, stream>>>(arows, gcount, N_EDGES);
  bucket_scan_kernel<<<1, 512, 0, stream>>>(gcount, bbase, gcursor);
  int nblkS = (N_EDGES + 256 * S_EPT - 1) / (256 * S_EPT);   // 391
  bucket_scatter_kernel<<<nblkS, 256, 0, stream>>>(arows, acols, avals, gcursor, packed, N_EDGES);

  // ---- t1 = x @ W1 ----
  gemm_kernel<<<dim3((N_NODES + 127) / 128, NHID / 128), 256, 0, stream>>>(
      x, W1, nullptr, B1, N_NODES, NFEAT, NHID);
  // ---- h = relu(A @ t1 + b1) ----
  spmm_bucket_kernel<<<NB, 512, 0, stream>>>(bbase, packed, B1, B2, b1, 1);
  // ---- t3 = A @ h ----
  spmm_bucket_kernel<<<NB, 512, 0, stream>>>(bbase, packed, B2, B1, nullptr, 0);
  // ---- out = t3 @ W2 + b2 ----
  gemm_kernel<<<dim3((N_NODES + 127) / 128, NFEAT / 128), 256, 0, stream>>>(
      B1, W2, b2, outp, N_NODES, NHID, NFEAT);
  // ---- folded classifier weights + classifiers ----
  wc_kernel<<<16, 256, 0, stream>>>(W2, b2, cW1, cb1, cW2, cb2, Wc1, bc1, Wc2, bc2);
  cls_kernel<<<1024, 256, 0, stream>>>(B1, Wc1, bc1, outp + (size_t)N_NODES * NFEAT, 0, TEXT_CNT);
  cls_kernel<<<1024, 256, 0, stream>>>(B1, Wc2, bc2,
      outp + (size_t)N_NODES * NFEAT + (size_t)TEXT_CNT * NCLASS, TEXT_CNT, N_NODES - TEXT_CNT);
}

// Round 3
// 810.651 us; speedup vs baseline: 7.0887x; 7.0887x over previous
//
#include <hip/hip_runtime.h>

#define N_NODES  100000
#define N_EDGES  3200000
#define NFEAT    256
#define NHID     128
#define NCLASS   16
#define TEXT_CNT 50000

#define RPB      256                          // rows per bucket
#define NB       ((N_NODES + RPB - 1) / RPB)  // 391 buckets
#define A_EPT    16                           // edges/thread, count pass
#define S_EPT    32                           // edges/thread, scatter pass

// ---------------- bucket count (LDS-aggregated histogram) ----------------

__global__ __launch_bounds__(256) void bucket_count_kernel(const int* __restrict__ rows,
                                                           int* __restrict__ gcount, int E) {
  __shared__ int hist[NB];
  for (int i = threadIdx.x; i < NB; i += 256) hist[i] = 0;
  __syncthreads();
  int base = blockIdx.x * (256 * A_EPT);
#pragma unroll
  for (int i = 0; i < A_EPT; ++i) {
    int e = base + i * 256 + threadIdx.x;
    if (e < E) atomicAdd(&hist[rows[e] >> 8], 1);
  }
  __syncthreads();
  for (int i = threadIdx.x; i < NB; i += 256) {
    int v = hist[i];
    if (v) atomicAdd(&gcount[i], v);
  }
}

// ---------------- scan bucket counts -> bases + cursors ----------------

__global__ __launch_bounds__(512) void bucket_scan_kernel(const int* __restrict__ gcount,
                                                          int* __restrict__ bbase,
                                                          int* __restrict__ gcursor) {
  __shared__ int s[512];
  int t = threadIdx.x;
  int v = (t < NB) ? gcount[t] : 0;
  s[t] = v;
  __syncthreads();
  for (int off = 1; off < 512; off <<= 1) {
    int u = (t >= off) ? s[t - off] : 0;
    __syncthreads();
    s[t] += u;
    __syncthreads();
  }
  if (t < NB) {
    int ex = s[t] - v;
    bbase[t] = ex;
    gcursor[t] = ex;
  }
  if (t == 0) bbase[NB] = N_EDGES;
}

// ---------------- multi-split scatter: edges -> bucket-grouped packed ----------------
// packed[p] = { (rowlocal<<17) | col , float_bits(val) }

__global__ __launch_bounds__(256) void bucket_scatter_kernel(const int* __restrict__ rows,
                                                             const int* __restrict__ cols,
                                                             const float* __restrict__ vals,
                                                             int* __restrict__ gcursor,
                                                             int2* __restrict__ packed, int E) {
  __shared__ int hist[NB];
  __shared__ int cur[NB];
  for (int i = threadIdx.x; i < NB; i += 256) hist[i] = 0;
  __syncthreads();
  int base = blockIdx.x * (256 * S_EPT);
#pragma unroll
  for (int i = 0; i < S_EPT; ++i) {
    int e = base + i * 256 + threadIdx.x;
    if (e < E) atomicAdd(&hist[rows[e] >> 8], 1);
  }
  __syncthreads();
  for (int i = threadIdx.x; i < NB; i += 256) {
    int h = hist[i];
    cur[i] = h ? atomicAdd(&gcursor[i], h) : 0;
  }
  __syncthreads();
#pragma unroll
  for (int i = 0; i < S_EPT; ++i) {
    int e = base + i * 256 + threadIdx.x;
    if (e < E) {
      int r = rows[e];
      int b = r >> 8;
      int p = atomicAdd(&cur[b], 1);
      packed[p] = make_int2(((r & 255) << 17) | cols[e], __float_as_int(vals[e]));
    }
  }
}

// ---------------- per-bucket CSR finalize ----------------
// One block per bucket: histogram local rows, scan -> row_ptr, rescatter into
// row-grouped order within the bucket's contiguous (L2-resident) window.

__global__ __launch_bounds__(256) void csr_finalize_kernel(const int* __restrict__ bbase,
                                                           const int2* __restrict__ packed_in,
                                                           int2* __restrict__ packed_out,
                                                           int* __restrict__ row_ptr) {
  __shared__ int hist[RPB];
  __shared__ int cur[RPB];
  int b = blockIdx.x;
  int s = bbase[b], e = bbase[b + 1];
  int t = threadIdx.x;
  hist[t] = 0;
  __syncthreads();
  for (int i = s + t; i < e; i += 256)
    atomicAdd(&hist[packed_in[i].x >> 17], 1);
  __syncthreads();
  int v = hist[t];
  cur[t] = v;
  __syncthreads();
  for (int off = 1; off < 256; off <<= 1) {
    int u = (t >= off) ? cur[t - off] : 0;
    __syncthreads();
    cur[t] += u;
    __syncthreads();
  }
  int gbase = s + cur[t] - v;   // global start of local row t
  int row = b * RPB + t;
  if (row < N_NODES) row_ptr[row] = gbase;
  if (b == 0 && t == 0) row_ptr[N_NODES] = N_EDGES;
  __syncthreads();
  cur[t] = gbase;
  __syncthreads();
  for (int i = s + t; i < e; i += 256) {
    int2 pk = packed_in[i];
    int r = pk.x >> 17;
    int p = atomicAdd(&cur[r], 1);
    packed_out[p] = make_int2(pk.x & 0x1FFFF, pk.y);
  }
}

// ---------------- CSR SpMM, D=128, wave per row ----------------
// dst[r,:] = sum_e val[e]*src[col[e],:]  (+bias, relu optional)

__global__ __launch_bounds__(256) void spmm_csr_kernel(const int* __restrict__ row_ptr,
                                                       const int2* __restrict__ packed,
                                                       const float* __restrict__ src,
                                                       float* __restrict__ dst,
                                                       const float* __restrict__ bias,
                                                       int relu, int nrows) {
  int lane = threadIdx.x & 63;
  int row = blockIdx.x * 4 + (threadIdx.x >> 6);
  if (row >= nrows) return;
  int s = row_ptr[row];
  int e = row_ptr[row + 1];
  const float2* src2 = (const float2*)src;
  float accx = 0.f, accy = 0.f;
  int i = s;
  for (; i + 4 <= e; i += 4) {
    int2 p0 = packed[i], p1 = packed[i + 1], p2 = packed[i + 2], p3 = packed[i + 3];
    float2 d0 = src2[(size_t)p0.x * 64 + lane];
    float2 d1 = src2[(size_t)p1.x * 64 + lane];
    float2 d2 = src2[(size_t)p2.x * 64 + lane];
    float2 d3 = src2[(size_t)p3.x * 64 + lane];
    float v0 = __int_as_float(p0.y), v1 = __int_as_float(p1.y);
    float v2 = __int_as_float(p2.y), v3 = __int_as_float(p3.y);
    accx += v0 * d0.x; accy += v0 * d0.y;
    accx += v1 * d1.x; accy += v1 * d1.y;
    accx += v2 * d2.x; accy += v2 * d2.y;
    accx += v3 * d3.x; accy += v3 * d3.y;
  }
  for (; i < e; ++i) {
    int2 pk = packed[i];
    float v = __int_as_float(pk.y);
    float2 d = src2[(size_t)pk.x * 64 + lane];
    accx += v * d.x; accy += v * d.y;
  }
  if (bias) { accx += bias[2 * lane]; accy += bias[2 * lane + 1]; }
  if (relu) { accx = fmaxf(accx, 0.f); accy = fmaxf(accy, 0.f); }
  float2 r; r.x = accx; r.y = accy;
  ((float2*)dst)[(size_t)row * 64 + lane] = r;
}

// ---------------- FP32 tiled GEMM: C[M,N] = A[M,K] @ B[K,N] (+bias) ----------------
// BM=128, BN=128, BK=16, 256 threads, 8x8 per thread.

__global__ __launch_bounds__(256) void gemm_kernel(const float* __restrict__ A,
                                                   const float* __restrict__ B,
                                                   const float* __restrict__ bias,
                                                   float* __restrict__ C,
                                                   int M, int K, int N) {
  __shared__ float As[16][132];
  __shared__ float Bs[16][132];
  int tid = threadIdx.x;
  int tx = tid & 15;
  int ty = tid >> 4;
  int brow = blockIdx.x * 128;
  int bcol = blockIdx.y * 128;

  float acc[8][8];
#pragma unroll
  for (int i = 0; i < 8; ++i)
#pragma unroll
    for (int j = 0; j < 8; ++j) acc[i][j] = 0.f;

  for (int k0 = 0; k0 < K; k0 += 16) {
#pragma unroll
    for (int li = 0; li < 2; ++li) {
      int idx = tid + li * 256;
      int r = idx >> 2;
      int kq = (idx & 3) << 2;
      int gr = brow + r;
      float4 v = make_float4(0.f, 0.f, 0.f, 0.f);
      if (gr < M) v = *(const float4*)&A[(size_t)gr * K + k0 + kq];
      As[kq + 0][r] = v.x;
      As[kq + 1][r] = v.y;
      As[kq + 2][r] = v.z;
      As[kq + 3][r] = v.w;
    }
#pragma unroll
    for (int li = 0; li < 2; ++li) {
      int idx = tid + li * 256;
      int kk = idx >> 5;
      int nq = (idx & 31) << 2;
      float4 v = *(const float4*)&B[(size_t)(k0 + kk) * N + bcol + nq];
      *(float4*)&Bs[kk][nq] = v;
    }
    __syncthreads();

#pragma unroll
    for (int kk = 0; kk < 16; ++kk) {
      float a[8], b[8];
      *(float4*)&a[0] = *(float4*)&As[kk][ty * 8];
      *(float4*)&a[4] = *(float4*)&As[kk][ty * 8 + 4];
      *(float4*)&b[0] = *(float4*)&Bs[kk][tx * 8];
      *(float4*)&b[4] = *(float4*)&Bs[kk][tx * 8 + 4];
#pragma unroll
      for (int i = 0; i < 8; ++i)
#pragma unroll
        for (int j = 0; j < 8; ++j) acc[i][j] += a[i] * b[j];
    }
    __syncthreads();
  }

  float bv[8];
#pragma unroll
  for (int j = 0; j < 8; ++j)
    bv[j] = bias ? bias[bcol + tx * 8 + j] : 0.f;

#pragma unroll
  for (int i = 0; i < 8; ++i) {
    int row = brow + ty * 8 + i;
    if (row < M) {
      float4 o0, o1;
      o0.x = acc[i][0] + bv[0]; o0.y = acc[i][1] + bv[1];
      o0.z = acc[i][2] + bv[2]; o0.w = acc[i][3] + bv[3];
      o1.x = acc[i][4] + bv[4]; o1.y = acc[i][5] + bv[5];
      o1.z = acc[i][6] + bv[6]; o1.w = acc[i][7] + bv[7];
      *(float4*)&C[(size_t)row * N + bcol + tx * 8] = o0;
      *(float4*)&C[(size_t)row * N + bcol + tx * 8 + 4] = o1;
    }
  }
}

// ---------------- fold classifier weights: Wc = W2 @ cW, bc = cb + b2 @ cW ----------------

__global__ __launch_bounds__(256) void wc_kernel(const float* __restrict__ W2,
                                                 const float* __restrict__ b2,
                                                 const float* __restrict__ cW1,
                                                 const float* __restrict__ cb1,
                                                 const float* __restrict__ cW2,
                                                 const float* __restrict__ cb2,
                                                 float* __restrict__ Wc1, float* __restrict__ bc1,
                                                 float* __restrict__ Wc2, float* __restrict__ bc2) {
  int idx = blockIdx.x * 256 + threadIdx.x;   // 0..4095
  int set = idx >> 11;
  int e = idx & 2047;
  int i = e >> 4;
  int c = e & 15;
  const float* cw = set ? cW2 : cW1;
  float acc = 0.f;
  for (int k = 0; k < NFEAT; ++k)
    acc += W2[(size_t)i * NFEAT + k] * cw[k * NCLASS + c];
  (set ? Wc2 : Wc1)[e] = acc;
  if (idx < 32) {
    int s2 = idx >> 4, c2 = idx & 15;
    const float* cwb = s2 ? cW2 : cW1;
    float b = (s2 ? cb2 : cb1)[c2];
    for (int k = 0; k < NFEAT; ++k) b += b2[k] * cwb[k * NCLASS + c2];
    (s2 ? bc2 : bc1)[c2] = b;
  }
}

// ---------------- classifier: cls[r,:] = t3[row0+r,:] @ Wc + bc ----------------

__global__ __launch_bounds__(256) void cls_kernel(const float* __restrict__ t3,
                                                  const float* __restrict__ Wc,
                                                  const float* __restrict__ bc,
                                                  float* __restrict__ outp,
                                                  int row0, int nrows) {
  int lane = threadIdx.x & 63;
  int wav = blockIdx.x * 4 + (threadIdx.x >> 6);
  int nw = gridDim.x * 4;
  int c = lane & 15;
  int kg = lane >> 4;
  float w[32];
#pragma unroll
  for (int j = 0; j < 32; ++j) w[j] = Wc[(kg * 32 + j) * NCLASS + c];
  float bcv = bc[c];
  for (int r = wav; r < nrows; r += nw) {
    const float4* rowp = (const float4*)&t3[(size_t)(row0 + r) * NHID + kg * 32];
    float acc = 0.f;
#pragma unroll
    for (int q = 0; q < 8; ++q) {
      float4 d = rowp[q];
      acc += d.x * w[q * 4 + 0] + d.y * w[q * 4 + 1] + d.z * w[q * 4 + 2] + d.w * w[q * 4 + 3];
    }
    acc += __shfl_xor(acc, 16);
    acc += __shfl_xor(acc, 32);
    if (lane < 16) outp[(size_t)r * NCLASS + lane] = acc + bcv;
  }
}

// ---------------- launch ----------------

extern "C" void kernel_launch(void* const* d_in, const int* in_sizes, int n_in,
                              void* d_out, int out_size, void* d_ws, size_t ws_size,
                              hipStream_t stream) {
  const float* x     = (const float*)d_in[0];
  const int*   arows = (const int*)d_in[1];
  const int*   acols = (const int*)d_in[2];
  const float* avals = (const float*)d_in[3];
  const float* W1    = (const float*)d_in[4];
  const float* b1    = (const float*)d_in[5];
  const float* W2    = (const float*)d_in[6];
  const float* b2    = (const float*)d_in[7];
  const float* cW1   = (const float*)d_in[8];
  const float* cb1   = (const float*)d_in[9];
  const float* cW2   = (const float*)d_in[10];
  const float* cb2   = (const float*)d_in[11];
  float* outp = (float*)d_out;

  char* ws = (char*)d_ws;
  size_t off = 0;
  auto alloc = [&](size_t bytes) -> void* {
    void* p = ws + off;
    off += (bytes + 255) & ~(size_t)255;
    return p;
  };
  float* B1      = (float*)alloc((size_t)N_NODES * NHID * 4);   // t1 / t3
  float* B2      = (float*)alloc((size_t)N_NODES * NHID * 4);   // h
  int2*  packedA = (int2*) alloc((size_t)N_EDGES * 8);          // bucket-grouped
  int2*  packedB = (int2*) alloc((size_t)N_EDGES * 8);          // row-grouped (CSR)
  int*   gcount  = (int*)  alloc((size_t)NB * 4);
  int*   bbase   = (int*)  alloc((size_t)(NB + 1) * 4);
  int*   gcursor = (int*)  alloc((size_t)NB * 4);
  int*   rowp    = (int*)  alloc((size_t)(N_NODES + 1) * 4);
  float* Wc1     = (float*)alloc(NHID * NCLASS * 4);
  float* Wc2     = (float*)alloc(NHID * NCLASS * 4);
  float* bc1     = (float*)alloc(64);
  float* bc2     = (float*)alloc(64);

  // ---- CSR build (bucket scatter + per-bucket finalize) ----
  hipMemsetAsync(gcount, 0, (size_t)NB * 4, stream);
  int nblkA = (N_EDGES + 256 * A_EPT - 1) / (256 * A_EPT);
  bucket_count_kernel<<<nblkA, 256, 0, stream>>>(arows, gcount, N_EDGES);
  bucket_scan_kernel<<<1, 512, 0, stream>>>(gcount, bbase, gcursor);
  int nblkS = (N_EDGES + 256 * S_EPT - 1) / (256 * S_EPT);
  bucket_scatter_kernel<<<nblkS, 256, 0, stream>>>(arows, acols, avals, gcursor, packedA, N_EDGES);
  csr_finalize_kernel<<<NB, 256, 0, stream>>>(bbase, packedA, packedB, rowp);

  // ---- t1 = x @ W1 ----
  gemm_kernel<<<dim3((N_NODES + 127) / 128, NHID / 128), 256, 0, stream>>>(
      x, W1, nullptr, B1, N_NODES, NFEAT, NHID);
  // ---- h = relu(A @ t1 + b1) ----
  spmm_csr_kernel<<<(N_NODES + 3) / 4, 256, 0, stream>>>(rowp, packedB, B1, B2, b1, 1, N_NODES);
  // ---- t3 = A @ h ----
  spmm_csr_kernel<<<(N_NODES + 3) / 4, 256, 0, stream>>>(rowp, packedB, B2, B1, nullptr, 0, N_NODES);
  // ---- out = t3 @ W2 + b2 ----
  gemm_kernel<<<dim3((N_NODES + 127) / 128, NFEAT / 128), 256, 0, stream>>>(
      B1, W2, b2, outp, N_NODES, NHID, NFEAT);
  // ---- folded classifier weights + classifiers ----
  wc_kernel<<<16, 256, 0, stream>>>(W2, b2, cW1, cb1, cW2, cb2, Wc1, bc1, Wc2, bc2);
  cls_kernel<<<1024, 256, 0, stream>>>(B1, Wc1, bc1, outp + (size_t)N_NODES * NFEAT, 0, TEXT_CNT);
  cls_kernel<<<1024, 256, 0, stream>>>(B1, Wc2, bc2,
      outp + (size_t)N_NODES * NFEAT + (size_t)TEXT_CNT * NCLASS, TEXT_CNT, N_NODES - TEXT_CNT);
}

// Round 4
// 525.105 us; speedup vs baseline: 10.9434x; 1.5438x over previous
//
#include <hip/hip_runtime.h>

#define N_NODES  100000
#define N_EDGES  3200000
#define NFEAT    256
#define NHID     128
#define NCLASS   16
#define TEXT_CNT 50000

#define RPB      256                          // rows per bucket
#define NB       ((N_NODES + RPB - 1) / RPB)  // 391 buckets
#define A_EPT    16                           // edges/thread, count pass
#define S_EPT    32                           // edges/thread, scatter pass

typedef unsigned int uint;
typedef __bf16 bf16x8 __attribute__((ext_vector_type(8)));
typedef __bf16 bf16x4 __attribute__((ext_vector_type(4)));
typedef float f32x4 __attribute__((ext_vector_type(4)));

__device__ inline uint bf16_rne(float f) {
  uint u = __float_as_uint(f);
  return (u + 0x7fffu + ((u >> 16) & 1u)) >> 16;
}
__device__ inline float bf_lo(uint u) { return __uint_as_float(u << 16); }
__device__ inline float bf_hi(uint u) { return __uint_as_float(u & 0xffff0000u); }

// ---------------- bucket count (LDS-aggregated histogram) ----------------

__global__ __launch_bounds__(256) void bucket_count_kernel(const int* __restrict__ rows,
                                                           int* __restrict__ gcount, int E) {
  __shared__ int hist[NB];
  for (int i = threadIdx.x; i < NB; i += 256) hist[i] = 0;
  __syncthreads();
  int base = blockIdx.x * (256 * A_EPT);
#pragma unroll
  for (int i = 0; i < A_EPT; ++i) {
    int e = base + i * 256 + threadIdx.x;
    if (e < E) atomicAdd(&hist[rows[e] >> 8], 1);
  }
  __syncthreads();
  for (int i = threadIdx.x; i < NB; i += 256) {
    int v = hist[i];
    if (v) atomicAdd(&gcount[i], v);
  }
}

// ---------------- scan bucket counts -> bases + cursors ----------------

__global__ __launch_bounds__(512) void bucket_scan_kernel(const int* __restrict__ gcount,
                                                          int* __restrict__ bbase,
                                                          int* __restrict__ gcursor) {
  __shared__ int s[512];
  int t = threadIdx.x;
  int v = (t < NB) ? gcount[t] : 0;
  s[t] = v;
  __syncthreads();
  for (int off = 1; off < 512; off <<= 1) {
    int u = (t >= off) ? s[t - off] : 0;
    __syncthreads();
    s[t] += u;
    __syncthreads();
  }
  if (t < NB) {
    int ex = s[t] - v;
    bbase[t] = ex;
    gcursor[t] = ex;
  }
  if (t == 0) bbase[NB] = N_EDGES;
}

// ---------------- multi-split scatter: edges -> bucket-grouped packed ----------------

__global__ __launch_bounds__(256) void bucket_scatter_kernel(const int* __restrict__ rows,
                                                             const int* __restrict__ cols,
                                                             const float* __restrict__ vals,
                                                             int* __restrict__ gcursor,
                                                             int2* __restrict__ packed, int E) {
  __shared__ int hist[NB];
  __shared__ int cur[NB];
  for (int i = threadIdx.x; i < NB; i += 256) hist[i] = 0;
  __syncthreads();
  int base = blockIdx.x * (256 * S_EPT);
#pragma unroll
  for (int i = 0; i < S_EPT; ++i) {
    int e = base + i * 256 + threadIdx.x;
    if (e < E) atomicAdd(&hist[rows[e] >> 8], 1);
  }
  __syncthreads();
  for (int i = threadIdx.x; i < NB; i += 256) {
    int h = hist[i];
    cur[i] = h ? atomicAdd(&gcursor[i], h) : 0;
  }
  __syncthreads();
#pragma unroll
  for (int i = 0; i < S_EPT; ++i) {
    int e = base + i * 256 + threadIdx.x;
    if (e < E) {
      int r = rows[e];
      int b = r >> 8;
      int p = atomicAdd(&cur[b], 1);
      packed[p] = make_int2(((r & 255) << 17) | cols[e], __float_as_int(vals[e]));
    }
  }
}

// ---------------- per-bucket CSR finalize ----------------

__global__ __launch_bounds__(256) void csr_finalize_kernel(const int* __restrict__ bbase,
                                                           const int2* __restrict__ packed_in,
                                                           int2* __restrict__ packed_out,
                                                           int* __restrict__ row_ptr) {
  __shared__ int hist[RPB];
  __shared__ int cur[RPB];
  int b = blockIdx.x;
  int s = bbase[b], e = bbase[b + 1];
  int t = threadIdx.x;
  hist[t] = 0;
  __syncthreads();
  for (int i = s + t; i < e; i += 256)
    atomicAdd(&hist[packed_in[i].x >> 17], 1);
  __syncthreads();
  int v = hist[t];
  cur[t] = v;
  __syncthreads();
  for (int off = 1; off < 256; off <<= 1) {
    int u = (t >= off) ? cur[t - off] : 0;
    __syncthreads();
    cur[t] += u;
    __syncthreads();
  }
  int gbase = s + cur[t] - v;
  int row = b * RPB + t;
  if (row < N_NODES) row_ptr[row] = gbase;
  if (b == 0 && t == 0) row_ptr[N_NODES] = N_EDGES;
  __syncthreads();
  cur[t] = gbase;
  __syncthreads();
  for (int i = s + t; i < e; i += 256) {
    int2 pk = packed_in[i];
    int r = pk.x >> 17;
    int p = atomicAdd(&cur[r], 1);
    packed_out[p] = make_int2(pk.x & 0x1FFFF, pk.y);
  }
}

// ---------------- CSR SpMM over bf16 features, D=128, wave per row ----------------
// dst[r,:] = bf16( relu?( sum_e val[e]*src[col[e],:] + bias ) )

__global__ __launch_bounds__(256) void spmm_bf16_kernel(const int* __restrict__ row_ptr,
                                                        const int2* __restrict__ packed,
                                                        const uint* __restrict__ src,   // [n][64] dwords
                                                        uint* __restrict__ dst,         // [n][64] dwords
                                                        const float* __restrict__ bias,
                                                        int relu, int nrows) {
  int lane = threadIdx.x & 63;
  int row = blockIdx.x * 4 + (threadIdx.x >> 6);
  if (row >= nrows) return;
  int s = row_ptr[row];
  int e = row_ptr[row + 1];
  float a0 = 0.f, a1 = 0.f;
  int i = s;
  for (; i + 8 <= e; i += 8) {
    int2 p0 = packed[i + 0], p1 = packed[i + 1], p2 = packed[i + 2], p3 = packed[i + 3];
    int2 p4 = packed[i + 4], p5 = packed[i + 5], p6 = packed[i + 6], p7 = packed[i + 7];
    uint u0 = src[(size_t)p0.x * 64 + lane];
    uint u1 = src[(size_t)p1.x * 64 + lane];
    uint u2 = src[(size_t)p2.x * 64 + lane];
    uint u3 = src[(size_t)p3.x * 64 + lane];
    uint u4 = src[(size_t)p4.x * 64 + lane];
    uint u5 = src[(size_t)p5.x * 64 + lane];
    uint u6 = src[(size_t)p6.x * 64 + lane];
    uint u7 = src[(size_t)p7.x * 64 + lane];
    float v0 = __int_as_float(p0.y), v1 = __int_as_float(p1.y);
    float v2 = __int_as_float(p2.y), v3 = __int_as_float(p3.y);
    float v4 = __int_as_float(p4.y), v5 = __int_as_float(p5.y);
    float v6 = __int_as_float(p6.y), v7 = __int_as_float(p7.y);
    a0 += v0 * bf_lo(u0); a1 += v0 * bf_hi(u0);
    a0 += v1 * bf_lo(u1); a1 += v1 * bf_hi(u1);
    a0 += v2 * bf_lo(u2); a1 += v2 * bf_hi(u2);
    a0 += v3 * bf_lo(u3); a1 += v3 * bf_hi(u3);
    a0 += v4 * bf_lo(u4); a1 += v4 * bf_hi(u4);
    a0 += v5 * bf_lo(u5); a1 += v5 * bf_hi(u5);
    a0 += v6 * bf_lo(u6); a1 += v6 * bf_hi(u6);
    a0 += v7 * bf_lo(u7); a1 += v7 * bf_hi(u7);
  }
  for (; i < e; ++i) {
    int2 pk = packed[i];
    float v = __int_as_float(pk.y);
    uint u = src[(size_t)pk.x * 64 + lane];
    a0 += v * bf_lo(u); a1 += v * bf_hi(u);
  }
  if (bias) { a0 += bias[2 * lane]; a1 += bias[2 * lane + 1]; }
  if (relu) { a0 = fmaxf(a0, 0.f); a1 = fmaxf(a1, 0.f); }
  dst[(size_t)row * 64 + lane] = bf16_rne(a0) | (bf16_rne(a1) << 16);
}

// ---------------- transpose+convert weights: Wt[n][k] = bf16(W[k][n]) ----------------

__global__ __launch_bounds__(256) void wt_kernel(const float* __restrict__ W,
                                                 unsigned short* __restrict__ Wt,
                                                 int K, int N) {
  int idx = blockIdx.x * 256 + threadIdx.x;
  if (idx >= K * N) return;
  int n = idx / K, k = idx - n * K;
  Wt[idx] = (unsigned short)bf16_rne(W[(size_t)k * N + n]);
}

// ---------------- bf16 MFMA GEMM: C[M,N] = A[M,K] @ Bt^T (+bias) ----------------
// 128x128 tile, BK=32, 256 threads = 4 waves (2x2), 4x4 16x16x32 frags/wave.

template <int A_FP32, int OUT_BF16, int K, int N>
__global__ __launch_bounds__(256) void gemm_mfma_kernel(const void* __restrict__ Aptr,
                                                        const __bf16* __restrict__ Bt,  // [N][K]
                                                        const float* __restrict__ bias,
                                                        void* __restrict__ Cptr, int M) {
  __shared__ __bf16 As[128 * 40];
  __shared__ __bf16 Bs[128 * 40];
  int tid = threadIdx.x;
  int lane = tid & 63;
  int w = tid >> 6;
  int wr = w >> 1, wc = w & 1;
  int brow = blockIdx.x * 128;
  int bcol = blockIdx.y * 128;
  int r16 = lane & 15, kb = lane >> 4;

  f32x4 acc[4][4];
#pragma unroll
  for (int m = 0; m < 4; ++m)
#pragma unroll
    for (int n = 0; n < 4; ++n) acc[m][n] = (f32x4){0.f, 0.f, 0.f, 0.f};

  for (int k0 = 0; k0 < K; k0 += 32) {
    if (A_FP32) {
      const float* A = (const float*)Aptr;
#pragma unroll
      for (int i = 0; i < 4; ++i) {
        int idx = tid + i * 256;
        int row = idx >> 3;
        int kq = (idx & 7) << 2;
        int gr = brow + row;
        float4 v = make_float4(0.f, 0.f, 0.f, 0.f);
        if (gr < M) v = *(const float4*)&A[(size_t)gr * K + k0 + kq];
        bf16x4 o;
        o[0] = (__bf16)v.x; o[1] = (__bf16)v.y; o[2] = (__bf16)v.z; o[3] = (__bf16)v.w;
        *(bf16x4*)&As[row * 40 + kq] = o;
      }
    } else {
      const __bf16* A = (const __bf16*)Aptr;
#pragma unroll
      for (int i = 0; i < 2; ++i) {
        int idx = tid + i * 256;
        int row = idx >> 2;
        int kq = (idx & 3) << 3;
        int gr = brow + row;
        bf16x8 v = {};
        if (gr < M) v = *(const bf16x8*)&A[(size_t)gr * K + k0 + kq];
        *(bf16x8*)&As[row * 40 + kq] = v;
      }
    }
#pragma unroll
    for (int i = 0; i < 2; ++i) {
      int idx = tid + i * 256;
      int col = idx >> 2;
      int kq = (idx & 3) << 3;
      bf16x8 v = *(const bf16x8*)&Bt[(size_t)(bcol + col) * K + k0 + kq];
      *(bf16x8*)&Bs[col * 40 + kq] = v;
    }
    __syncthreads();

    bf16x8 a[4], b[4];
#pragma unroll
    for (int m = 0; m < 4; ++m)
      a[m] = *(bf16x8*)&As[(wr * 64 + m * 16 + r16) * 40 + kb * 8];
#pragma unroll
    for (int n = 0; n < 4; ++n)
      b[n] = *(bf16x8*)&Bs[(wc * 64 + n * 16 + r16) * 40 + kb * 8];
#pragma unroll
    for (int m = 0; m < 4; ++m)
#pragma unroll
      for (int n = 0; n < 4; ++n)
        acc[m][n] = __builtin_amdgcn_mfma_f32_16x16x32_bf16(a[m], b[n], acc[m][n], 0, 0, 0);
    __syncthreads();
  }

  int crow0 = brow + wr * 64;
  int ccol0 = bcol + wc * 64;
#pragma unroll
  for (int n = 0; n < 4; ++n) {
    int col = ccol0 + n * 16 + r16;
    float bv = bias ? bias[col] : 0.f;
#pragma unroll
    for (int m = 0; m < 4; ++m) {
#pragma unroll
      for (int r = 0; r < 4; ++r) {
        int row = crow0 + m * 16 + kb * 4 + r;
        if (row < M) {
          float val = acc[m][n][r] + bv;
          if (OUT_BF16)
            ((unsigned short*)Cptr)[(size_t)row * N + col] = (unsigned short)bf16_rne(val);
          else
            ((float*)Cptr)[(size_t)row * N + col] = val;
        }
      }
    }
  }
}

// ---------------- fold classifier weights: Wc = W2 @ cW, bc = cb + b2 @ cW ----------------

__global__ __launch_bounds__(256) void wc_kernel(const float* __restrict__ W2,
                                                 const float* __restrict__ b2,
                                                 const float* __restrict__ cW1,
                                                 const float* __restrict__ cb1,
                                                 const float* __restrict__ cW2,
                                                 const float* __restrict__ cb2,
                                                 float* __restrict__ Wc1, float* __restrict__ bc1,
                                                 float* __restrict__ Wc2, float* __restrict__ bc2) {
  int idx = blockIdx.x * 256 + threadIdx.x;   // 0..4095
  int set = idx >> 11;
  int e = idx & 2047;
  int i = e >> 4;
  int c = e & 15;
  const float* cw = set ? cW2 : cW1;
  float acc = 0.f;
  for (int k = 0; k < NFEAT; ++k)
    acc += W2[(size_t)i * NFEAT + k] * cw[k * NCLASS + c];
  (set ? Wc2 : Wc1)[e] = acc;
  if (idx < 32) {
    int s2 = idx >> 4, c2 = idx & 15;
    const float* cwb = s2 ? cW2 : cW1;
    float b = (s2 ? cb2 : cb1)[c2];
    for (int k = 0; k < NFEAT; ++k) b += b2[k] * cwb[k * NCLASS + c2];
    (s2 ? bc2 : bc1)[c2] = b;
  }
}

// ---------------- classifier over bf16 t3: cls[r,:] = t3[row0+r,:] @ Wc + bc ----------------

__global__ __launch_bounds__(256) void cls_kernel(const uint* __restrict__ t3,  // [n][64] dwords
                                                  const float* __restrict__ Wc,
                                                  const float* __restrict__ bc,
                                                  float* __restrict__ outp,
                                                  int row0, int nrows) {
  int lane = threadIdx.x & 63;
  int wav = blockIdx.x * 4 + (threadIdx.x >> 6);
  int nw = gridDim.x * 4;
  int c = lane & 15;
  int kg = lane >> 4;
  float w[32];
#pragma unroll
  for (int j = 0; j < 32; ++j) w[j] = Wc[(kg * 32 + j) * NCLASS + c];
  float bcv = bc[c];
  for (int r = wav; r < nrows; r += nw) {
    const uint4* rp = (const uint4*)&t3[(size_t)(row0 + r) * 64 + kg * 16];
    float acc = 0.f;
#pragma unroll
    for (int q = 0; q < 4; ++q) {
      uint4 u = rp[q];
      acc += bf_lo(u.x) * w[q * 8 + 0] + bf_hi(u.x) * w[q * 8 + 1]
           + bf_lo(u.y) * w[q * 8 + 2] + bf_hi(u.y) * w[q * 8 + 3]
           + bf_lo(u.z) * w[q * 8 + 4] + bf_hi(u.z) * w[q * 8 + 5]
           + bf_lo(u.w) * w[q * 8 + 6] + bf_hi(u.w) * w[q * 8 + 7];
    }
    acc += __shfl_xor(acc, 16);
    acc += __shfl_xor(acc, 32);
    if (lane < 16) outp[(size_t)r * NCLASS + lane] = acc + bcv;
  }
}

// ---------------- launch ----------------

extern "C" void kernel_launch(void* const* d_in, const int* in_sizes, int n_in,
                              void* d_out, int out_size, void* d_ws, size_t ws_size,
                              hipStream_t stream) {
  const float* x     = (const float*)d_in[0];
  const int*   arows = (const int*)d_in[1];
  const int*   acols = (const int*)d_in[2];
  const float* avals = (const float*)d_in[3];
  const float* W1    = (const float*)d_in[4];
  const float* b1    = (const float*)d_in[5];
  const float* W2    = (const float*)d_in[6];
  const float* b2    = (const float*)d_in[7];
  const float* cW1   = (const float*)d_in[8];
  const float* cb1   = (const float*)d_in[9];
  const float* cW2   = (const float*)d_in[10];
  const float* cb2   = (const float*)d_in[11];
  float* outp = (float*)d_out;

  char* ws = (char*)d_ws;
  size_t off = 0;
  auto alloc = [&](size_t bytes) -> void* {
    void* p = ws + off;
    off += (bytes + 255) & ~(size_t)255;
    return p;
  };
  uint*  t1u     = (uint*) alloc((size_t)N_NODES * 64 * 4);   // bf16 [N][128]
  uint*  hu      = (uint*) alloc((size_t)N_NODES * 64 * 4);   // bf16 [N][128]
  uint*  t3u     = (uint*) alloc((size_t)N_NODES * 64 * 4);   // bf16 [N][128]
  int2*  packedA = (int2*) alloc((size_t)N_EDGES * 8);        // bucket-grouped
  int2*  packedB = (int2*) alloc((size_t)N_EDGES * 8);        // row-grouped (CSR)
  int*   gcount  = (int*)  alloc((size_t)NB * 4);
  int*   bbase   = (int*)  alloc((size_t)(NB + 1) * 4);
  int*   gcursor = (int*)  alloc((size_t)NB * 4);
  int*   rowp    = (int*)  alloc((size_t)(N_NODES + 1) * 4);
  unsigned short* W1t = (unsigned short*)alloc((size_t)NHID * NFEAT * 2);  // [128][256]
  unsigned short* W2t = (unsigned short*)alloc((size_t)NFEAT * NHID * 2);  // [256][128]
  float* Wc1     = (float*)alloc(NHID * NCLASS * 4);
  float* Wc2     = (float*)alloc(NHID * NCLASS * 4);
  float* bc1     = (float*)alloc(64);
  float* bc2     = (float*)alloc(64);

  // ---- CSR build (bucket scatter + per-bucket finalize) ----
  hipMemsetAsync(gcount, 0, (size_t)NB * 4, stream);
  int nblkA = (N_EDGES + 256 * A_EPT - 1) / (256 * A_EPT);
  bucket_count_kernel<<<nblkA, 256, 0, stream>>>(arows, gcount, N_EDGES);
  bucket_scan_kernel<<<1, 512, 0, stream>>>(gcount, bbase, gcursor);
  int nblkS = (N_EDGES + 256 * S_EPT - 1) / (256 * S_EPT);
  bucket_scatter_kernel<<<nblkS, 256, 0, stream>>>(arows, acols, avals, gcursor, packedA, N_EDGES);
  csr_finalize_kernel<<<NB, 256, 0, stream>>>(bbase, packedA, packedB, rowp);

  // ---- weight prep: W1t = bf16(W1^T), W2t = bf16(W2^T) ----
  wt_kernel<<<(NFEAT * NHID + 255) / 256, 256, 0, stream>>>(W1, W1t, NFEAT, NHID);
  wt_kernel<<<(NFEAT * NHID + 255) / 256, 256, 0, stream>>>(W2, W2t, NHID, NFEAT);

  int mblk = (N_NODES + 127) / 128;  // 782
  // ---- t1 = bf16(x @ W1) ----
  gemm_mfma_kernel<1, 1, NFEAT, NHID><<<dim3(mblk, 1), 256, 0, stream>>>(
      x, (const __bf16*)W1t, nullptr, t1u, N_NODES);
  // ---- h = bf16(relu(A @ t1 + b1)) ----
  spmm_bf16_kernel<<<(N_NODES + 3) / 4, 256, 0, stream>>>(rowp, packedB, t1u, hu, b1, 1, N_NODES);
  // ---- t3 = bf16(A @ h) ----
  spmm_bf16_kernel<<<(N_NODES + 3) / 4, 256, 0, stream>>>(rowp, packedB, hu, t3u, nullptr, 0, N_NODES);
  // ---- out = t3 @ W2 + b2 (fp32 out) ----
  gemm_mfma_kernel<0, 0, NHID, NFEAT><<<dim3(mblk, 2), 256, 0, stream>>>(
      t3u, (const __bf16*)W2t, b2, outp, N_NODES);
  // ---- folded classifier weights + classifiers ----
  wc_kernel<<<16, 256, 0, stream>>>(W2, b2, cW1, cb1, cW2, cb2, Wc1, bc1, Wc2, bc2);
  cls_kernel<<<1024, 256, 0, stream>>>(t3u, Wc1, bc1, outp + (size_t)N_NODES * NFEAT, 0, TEXT_CNT);
  cls_kernel<<<1024, 256, 0, stream>>>(t3u, Wc2, bc2,
      outp + (size_t)N_NODES * NFEAT + (size_t)TEXT_CNT * NCLASS, TEXT_CNT, N_NODES - TEXT_CNT);
}

// Round 5
// 491.821 us; speedup vs baseline: 11.6840x; 1.0677x over previous
//
#include <hip/hip_runtime.h>

#define N_NODES  100000
#define N_EDGES  3200000
#define NFEAT    256
#define NHID     128
#define NCLASS   16
#define TEXT_CNT 50000

#define RPB      256                          // rows per bucket
#define NB       ((N_NODES + RPB - 1) / RPB)  // 391 buckets
#define CAP      16384                        // fixed bucket capacity (2^14), E[cnt]=8192
#define S_EPT    32                           // edges/thread, scatter pass

typedef unsigned int uint;
typedef __bf16 bf16x8 __attribute__((ext_vector_type(8)));
typedef __bf16 bf16x4 __attribute__((ext_vector_type(4)));
typedef float f32x4 __attribute__((ext_vector_type(4)));

__device__ inline uint bf16_rne(float f) {
  uint u = __float_as_uint(f);
  return (u + 0x7fffu + ((u >> 16) & 1u)) >> 16;
}
__device__ inline float bf_lo(uint u) { return __uint_as_float(u << 16); }
__device__ inline float bf_hi(uint u) { return __uint_as_float(u & 0xffff0000u); }

// ---------------- cursor init: gcursor[b] = b*CAP ----------------

__global__ __launch_bounds__(256) void init_cursor_kernel(int* __restrict__ gcursor) {
  int t = blockIdx.x * 256 + threadIdx.x;
  if (t < NB) gcursor[t] = t * CAP;
}

// ---------------- multi-split scatter into fixed-capacity buckets ----------------
// packedA[p] = { (rowlocal<<17) | col , float_bits(val) }

__global__ __launch_bounds__(256) void bucket_scatter_kernel(const int* __restrict__ rows,
                                                             const int* __restrict__ cols,
                                                             const float* __restrict__ vals,
                                                             int* __restrict__ gcursor,
                                                             int2* __restrict__ packed, int E) {
  __shared__ int hist[NB];
  __shared__ int cur[NB];
  for (int i = threadIdx.x; i < NB; i += 256) hist[i] = 0;
  __syncthreads();
  int base = blockIdx.x * (256 * S_EPT);
#pragma unroll
  for (int i = 0; i < S_EPT; ++i) {
    int e = base + i * 256 + threadIdx.x;
    if (e < E) atomicAdd(&hist[rows[e] >> 8], 1);
  }
  __syncthreads();
  for (int i = threadIdx.x; i < NB; i += 256) {
    int h = hist[i];
    cur[i] = h ? atomicAdd(&gcursor[i], h) : 0;
  }
  __syncthreads();
#pragma unroll
  for (int i = 0; i < S_EPT; ++i) {
    int e = base + i * 256 + threadIdx.x;
    if (e < E) {
      int r = rows[e];
      int b = r >> 8;
      int p = atomicAdd(&cur[b], 1);
      if (p < ((b + 1) << 14))   // capacity guard (never hit at 90 sigma)
        packed[p] = make_int2(((r & 255) << 17) | cols[e], __float_as_int(vals[e]));
    }
  }
}

// ---------------- scan bucket counts (from cursors) -> global CSR bases ----------------

__global__ __launch_bounds__(512) void bucket_scan_kernel(const int* __restrict__ gcursor,
                                                          int* __restrict__ bbase) {
  __shared__ int s[512];
  int t = threadIdx.x;
  int v = (t < NB) ? (gcursor[t] - t * CAP) : 0;
  s[t] = v;
  __syncthreads();
  for (int off = 1; off < 512; off <<= 1) {
    int u = (t >= off) ? s[t - off] : 0;
    __syncthreads();
    s[t] += u;
    __syncthreads();
  }
  if (t < NB) bbase[t] = s[t] - v;
  if (t == 0) bbase[NB] = N_EDGES;
}

// ---------------- per-bucket CSR finalize (4x latency-unrolled) ----------------
// packedB[p] = { col<<8 (byte offset of feature row), float_bits(val) }

__global__ __launch_bounds__(256) void csr_finalize_kernel(const int* __restrict__ bbase,
                                                           const int2* __restrict__ packed_in,
                                                           int2* __restrict__ packed_out,
                                                           int* __restrict__ row_ptr) {
  __shared__ int hist[RPB];
  __shared__ int cur[RPB];
  int b = blockIdx.x;
  int s0 = b * CAP;
  int gout = bbase[b];
  int cnt = bbase[b + 1] - gout;
  int end = s0 + cnt;
  int t = threadIdx.x;
  hist[t] = 0;
  __syncthreads();
  {
    int i = s0 + t;
    for (; i + 768 < end; i += 1024) {
      int2 a0 = packed_in[i], a1 = packed_in[i + 256];
      int2 a2 = packed_in[i + 512], a3 = packed_in[i + 768];
      atomicAdd(&hist[a0.x >> 17], 1);
      atomicAdd(&hist[a1.x >> 17], 1);
      atomicAdd(&hist[a2.x >> 17], 1);
      atomicAdd(&hist[a3.x >> 17], 1);
    }
    for (; i < end; i += 256) atomicAdd(&hist[packed_in[i].x >> 17], 1);
  }
  __syncthreads();
  int v = hist[t];
  cur[t] = v;
  __syncthreads();
  for (int off = 1; off < 256; off <<= 1) {
    int u = (t >= off) ? cur[t - off] : 0;
    __syncthreads();
    cur[t] += u;
    __syncthreads();
  }
  int rbase = gout + cur[t] - v;   // global CSR start of local row t
  int row = b * RPB + t;
  if (row < N_NODES) row_ptr[row] = rbase;
  if (b == 0 && t == 0) row_ptr[N_NODES] = N_EDGES;
  __syncthreads();
  cur[t] = rbase;
  __syncthreads();
  {
    int i = s0 + t;
    for (; i + 768 < end; i += 1024) {
      int2 a0 = packed_in[i], a1 = packed_in[i + 256];
      int2 a2 = packed_in[i + 512], a3 = packed_in[i + 768];
      int p0 = atomicAdd(&cur[a0.x >> 17], 1);
      int p1 = atomicAdd(&cur[a1.x >> 17], 1);
      int p2 = atomicAdd(&cur[a2.x >> 17], 1);
      int p3 = atomicAdd(&cur[a3.x >> 17], 1);
      packed_out[p0] = make_int2((a0.x & 0x1FFFF) << 8, a0.y);
      packed_out[p1] = make_int2((a1.x & 0x1FFFF) << 8, a1.y);
      packed_out[p2] = make_int2((a2.x & 0x1FFFF) << 8, a2.y);
      packed_out[p3] = make_int2((a3.x & 0x1FFFF) << 8, a3.y);
    }
    for (; i < end; i += 256) {
      int2 pk = packed_in[i];
      int p = atomicAdd(&cur[pk.x >> 17], 1);
      packed_out[p] = make_int2((pk.x & 0x1FFFF) << 8, pk.y);
    }
  }
}

// ---------------- CSR SpMM over bf16 features, D=128, wave per row ----------------

__global__ __launch_bounds__(256) void spmm_bf16_kernel(const int* __restrict__ row_ptr,
                                                        const int2* __restrict__ packed,
                                                        const uint* __restrict__ src,   // [n][64] dwords
                                                        uint* __restrict__ dst,         // [n][64] dwords
                                                        const float* __restrict__ bias,
                                                        int relu, int nrows) {
  int lane = threadIdx.x & 63;
  int row = blockIdx.x * 4 + (threadIdx.x >> 6);
  if (row >= nrows) return;
  int s = row_ptr[row];
  int e = row_ptr[row + 1];
  const char* srcb = (const char*)src + (lane << 2);
  float a0 = 0.f, a1 = 0.f;
  int i = s;
  for (; i + 8 <= e; i += 8) {
    int2 p0 = packed[i + 0], p1 = packed[i + 1], p2 = packed[i + 2], p3 = packed[i + 3];
    int2 p4 = packed[i + 4], p5 = packed[i + 5], p6 = packed[i + 6], p7 = packed[i + 7];
    uint u0 = *(const uint*)(srcb + (uint)p0.x);
    uint u1 = *(const uint*)(srcb + (uint)p1.x);
    uint u2 = *(const uint*)(srcb + (uint)p2.x);
    uint u3 = *(const uint*)(srcb + (uint)p3.x);
    uint u4 = *(const uint*)(srcb + (uint)p4.x);
    uint u5 = *(const uint*)(srcb + (uint)p5.x);
    uint u6 = *(const uint*)(srcb + (uint)p6.x);
    uint u7 = *(const uint*)(srcb + (uint)p7.x);
    float v0 = __int_as_float(p0.y), v1 = __int_as_float(p1.y);
    float v2 = __int_as_float(p2.y), v3 = __int_as_float(p3.y);
    float v4 = __int_as_float(p4.y), v5 = __int_as_float(p5.y);
    float v6 = __int_as_float(p6.y), v7 = __int_as_float(p7.y);
    a0 += v0 * bf_lo(u0); a1 += v0 * bf_hi(u0);
    a0 += v1 * bf_lo(u1); a1 += v1 * bf_hi(u1);
    a0 += v2 * bf_lo(u2); a1 += v2 * bf_hi(u2);
    a0 += v3 * bf_lo(u3); a1 += v3 * bf_hi(u3);
    a0 += v4 * bf_lo(u4); a1 += v4 * bf_hi(u4);
    a0 += v5 * bf_lo(u5); a1 += v5 * bf_hi(u5);
    a0 += v6 * bf_lo(u6); a1 += v6 * bf_hi(u6);
    a0 += v7 * bf_lo(u7); a1 += v7 * bf_hi(u7);
  }
  for (; i < e; ++i) {
    int2 pk = packed[i];
    float v = __int_as_float(pk.y);
    uint u = *(const uint*)(srcb + (uint)pk.x);
    a0 += v * bf_lo(u); a1 += v * bf_hi(u);
  }
  if (bias) { a0 += bias[2 * lane]; a1 += bias[2 * lane + 1]; }
  if (relu) { a0 = fmaxf(a0, 0.f); a1 = fmaxf(a1, 0.f); }
  dst[(size_t)row * 64 + lane] = bf16_rne(a0) | (bf16_rne(a1) << 16);
}

// ---------------- transpose+convert weights: Wt[n][k] = bf16(W[k][n]) ----------------

__global__ __launch_bounds__(256) void wt_kernel(const float* __restrict__ W,
                                                 unsigned short* __restrict__ Wt,
                                                 int K, int N) {
  int idx = blockIdx.x * 256 + threadIdx.x;
  if (idx >= K * N) return;
  int n = idx / K, k = idx - n * K;
  Wt[idx] = (unsigned short)bf16_rne(W[(size_t)k * N + n]);
}

// ---------------- bf16 MFMA GEMM: C[M,N] = A[M,K] @ Bt^T (+bias) ----------------
// 128x128 tile, BK=32, 256 threads = 4 waves (2x2), 4x4 16x16x32 frags/wave.

template <int A_FP32, int OUT_BF16, int K, int N>
__global__ __launch_bounds__(256) void gemm_mfma_kernel(const void* __restrict__ Aptr,
                                                        const __bf16* __restrict__ Bt,  // [N][K]
                                                        const float* __restrict__ bias,
                                                        void* __restrict__ Cptr, int M) {
  __shared__ __bf16 As[128 * 40];
  __shared__ __bf16 Bs[128 * 40];
  int tid = threadIdx.x;
  int lane = tid & 63;
  int w = tid >> 6;
  int wr = w >> 1, wc = w & 1;
  int brow = blockIdx.x * 128;
  int bcol = blockIdx.y * 128;
  int r16 = lane & 15, kb = lane >> 4;

  f32x4 acc[4][4];
#pragma unroll
  for (int m = 0; m < 4; ++m)
#pragma unroll
    for (int n = 0; n < 4; ++n) acc[m][n] = (f32x4){0.f, 0.f, 0.f, 0.f};

  for (int k0 = 0; k0 < K; k0 += 32) {
    if (A_FP32) {
      const float* A = (const float*)Aptr;
#pragma unroll
      for (int i = 0; i < 4; ++i) {
        int idx = tid + i * 256;
        int row = idx >> 3;
        int kq = (idx & 7) << 2;
        int gr = brow + row;
        float4 v = make_float4(0.f, 0.f, 0.f, 0.f);
        if (gr < M) v = *(const float4*)&A[(size_t)gr * K + k0 + kq];
        bf16x4 o;
        o[0] = (__bf16)v.x; o[1] = (__bf16)v.y; o[2] = (__bf16)v.z; o[3] = (__bf16)v.w;
        *(bf16x4*)&As[row * 40 + kq] = o;
      }
    } else {
      const __bf16* A = (const __bf16*)Aptr;
#pragma unroll
      for (int i = 0; i < 2; ++i) {
        int idx = tid + i * 256;
        int row = idx >> 2;
        int kq = (idx & 3) << 3;
        int gr = brow + row;
        bf16x8 v = {};
        if (gr < M) v = *(const bf16x8*)&A[(size_t)gr * K + k0 + kq];
        *(bf16x8*)&As[row * 40 + kq] = v;
      }
    }
#pragma unroll
    for (int i = 0; i < 2; ++i) {
      int idx = tid + i * 256;
      int col = idx >> 2;
      int kq = (idx & 3) << 3;
      bf16x8 v = *(const bf16x8*)&Bt[(size_t)(bcol + col) * K + k0 + kq];
      *(bf16x8*)&Bs[col * 40 + kq] = v;
    }
    __syncthreads();

    bf16x8 a[4], b[4];
#pragma unroll
    for (int m = 0; m < 4; ++m)
      a[m] = *(bf16x8*)&As[(wr * 64 + m * 16 + r16) * 40 + kb * 8];
#pragma unroll
    for (int n = 0; n < 4; ++n)
      b[n] = *(bf16x8*)&Bs[(wc * 64 + n * 16 + r16) * 40 + kb * 8];
#pragma unroll
    for (int m = 0; m < 4; ++m)
#pragma unroll
      for (int n = 0; n < 4; ++n)
        acc[m][n] = __builtin_amdgcn_mfma_f32_16x16x32_bf16(a[m], b[n], acc[m][n], 0, 0, 0);
    __syncthreads();
  }

  int crow0 = brow + wr * 64;
  int ccol0 = bcol + wc * 64;
#pragma unroll
  for (int n = 0; n < 4; ++n) {
    int col = ccol0 + n * 16 + r16;
    float bv = bias ? bias[col] : 0.f;
#pragma unroll
    for (int m = 0; m < 4; ++m) {
#pragma unroll
      for (int r = 0; r < 4; ++r) {
        int row = crow0 + m * 16 + kb * 4 + r;
        if (row < M) {
          float val = acc[m][n][r] + bv;
          if (OUT_BF16)
            ((unsigned short*)Cptr)[(size_t)row * N + col] = (unsigned short)bf16_rne(val);
          else
            ((float*)Cptr)[(size_t)row * N + col] = val;
        }
      }
    }
  }
}

// ---------------- fold classifier weights: Wc = W2 @ cW, bc = cb + b2 @ cW ----------------

__global__ __launch_bounds__(256) void wc_kernel(const float* __restrict__ W2,
                                                 const float* __restrict__ b2,
                                                 const float* __restrict__ cW1,
                                                 const float* __restrict__ cb1,
                                                 const float* __restrict__ cW2,
                                                 const float* __restrict__ cb2,
                                                 float* __restrict__ Wc1, float* __restrict__ bc1,
                                                 float* __restrict__ Wc2, float* __restrict__ bc2) {
  int idx = blockIdx.x * 256 + threadIdx.x;   // 0..4095
  int set = idx >> 11;
  int e = idx & 2047;
  int i = e >> 4;
  int c = e & 15;
  const float* cw = set ? cW2 : cW1;
  float acc = 0.f;
  for (int k = 0; k < NFEAT; ++k)
    acc += W2[(size_t)i * NFEAT + k] * cw[k * NCLASS + c];
  (set ? Wc2 : Wc1)[e] = acc;
  if (idx < 32) {
    int s2 = idx >> 4, c2 = idx & 15;
    const float* cwb = s2 ? cW2 : cW1;
    float b = (s2 ? cb2 : cb1)[c2];
    for (int k = 0; k < NFEAT; ++k) b += b2[k] * cwb[k * NCLASS + c2];
    (s2 ? bc2 : bc1)[c2] = b;
  }
}

// ---------------- classifier (both regions in one launch) ----------------

__global__ __launch_bounds__(256) void cls_kernel(const uint* __restrict__ t3,
                                                  const float* __restrict__ Wc1,
                                                  const float* __restrict__ bc1,
                                                  const float* __restrict__ Wc2,
                                                  const float* __restrict__ bc2,
                                                  float* __restrict__ out1,
                                                  float* __restrict__ out2) {
  int half = gridDim.x >> 1;
  int region = blockIdx.x >= half;
  int bid = region ? blockIdx.x - half : blockIdx.x;
  const float* Wc = region ? Wc2 : Wc1;
  const float* bc = region ? bc2 : bc1;
  float* outp = region ? out2 : out1;
  int row0 = region ? TEXT_CNT : 0;
  int nrows = region ? (N_NODES - TEXT_CNT) : TEXT_CNT;

  int lane = threadIdx.x & 63;
  int wav = bid * 4 + (threadIdx.x >> 6);
  int nw = half * 4;
  int c = lane & 15;
  int kg = lane >> 4;
  float w[32];
#pragma unroll
  for (int j = 0; j < 32; ++j) w[j] = Wc[(kg * 32 + j) * NCLASS + c];
  float bcv = bc[c];
  for (int r = wav; r < nrows; r += nw) {
    const uint4* rp = (const uint4*)&t3[(size_t)(row0 + r) * 64 + kg * 16];
    float acc = 0.f;
#pragma unroll
    for (int q = 0; q < 4; ++q) {
      uint4 u = rp[q];
      acc += bf_lo(u.x) * w[q * 8 + 0] + bf_hi(u.x) * w[q * 8 + 1]
           + bf_lo(u.y) * w[q * 8 + 2] + bf_hi(u.y) * w[q * 8 + 3]
           + bf_lo(u.z) * w[q * 8 + 4] + bf_hi(u.z) * w[q * 8 + 5]
           + bf_lo(u.w) * w[q * 8 + 6] + bf_hi(u.w) * w[q * 8 + 7];
    }
    acc += __shfl_xor(acc, 16);
    acc += __shfl_xor(acc, 32);
    if (lane < 16) outp[(size_t)r * NCLASS + lane] = acc + bcv;
  }
}

// ---------------- launch ----------------

extern "C" void kernel_launch(void* const* d_in, const int* in_sizes, int n_in,
                              void* d_out, int out_size, void* d_ws, size_t ws_size,
                              hipStream_t stream) {
  const float* x     = (const float*)d_in[0];
  const int*   arows = (const int*)d_in[1];
  const int*   acols = (const int*)d_in[2];
  const float* avals = (const float*)d_in[3];
  const float* W1    = (const float*)d_in[4];
  const float* b1    = (const float*)d_in[5];
  const float* W2    = (const float*)d_in[6];
  const float* b2    = (const float*)d_in[7];
  const float* cW1   = (const float*)d_in[8];
  const float* cb1   = (const float*)d_in[9];
  const float* cW2   = (const float*)d_in[10];
  const float* cb2   = (const float*)d_in[11];
  float* outp = (float*)d_out;

  char* ws = (char*)d_ws;
  size_t off = 0;
  auto alloc = [&](size_t bytes) -> void* {
    void* p = ws + off;
    off += (bytes + 255) & ~(size_t)255;
    return p;
  };
  uint*  t1u     = (uint*) alloc((size_t)N_NODES * 64 * 4);   // bf16 [N][128]
  uint*  hu      = (uint*) alloc((size_t)N_NODES * 64 * 4);   // bf16 [N][128]
  uint*  t3u     = (uint*) alloc((size_t)N_NODES * 64 * 4);   // bf16 [N][128]
  int2*  packedA = (int2*) alloc((size_t)NB * CAP * 8);       // fixed-cap buckets
  int2*  packedB = (int2*) alloc((size_t)N_EDGES * 8);        // row-grouped (CSR)
  int*   bbase   = (int*)  alloc((size_t)(NB + 1) * 4);
  int*   gcursor = (int*)  alloc((size_t)NB * 4);
  int*   rowp    = (int*)  alloc((size_t)(N_NODES + 1) * 4);
  unsigned short* W1t = (unsigned short*)alloc((size_t)NHID * NFEAT * 2);  // [128][256]
  unsigned short* W2t = (unsigned short*)alloc((size_t)NFEAT * NHID * 2);  // [256][128]
  float* Wc1     = (float*)alloc(NHID * NCLASS * 4);
  float* Wc2     = (float*)alloc(NHID * NCLASS * 4);
  float* bc1     = (float*)alloc(64);
  float* bc2     = (float*)alloc(64);

  // ---- CSR build (fixed-cap bucket scatter + scan + per-bucket finalize) ----
  init_cursor_kernel<<<(NB + 255) / 256, 256, 0, stream>>>(gcursor);
  int nblkS = (N_EDGES + 256 * S_EPT - 1) / (256 * S_EPT);   // 391
  bucket_scatter_kernel<<<nblkS, 256, 0, stream>>>(arows, acols, avals, gcursor, packedA, N_EDGES);
  bucket_scan_kernel<<<1, 512, 0, stream>>>(gcursor, bbase);
  csr_finalize_kernel<<<NB, 256, 0, stream>>>(bbase, packedA, packedB, rowp);

  // ---- weight prep ----
  wt_kernel<<<(NFEAT * NHID + 255) / 256, 256, 0, stream>>>(W1, W1t, NFEAT, NHID);
  wt_kernel<<<(NFEAT * NHID + 255) / 256, 256, 0, stream>>>(W2, W2t, NHID, NFEAT);
  wc_kernel<<<16, 256, 0, stream>>>(W2, b2, cW1, cb1, cW2, cb2, Wc1, bc1, Wc2, bc2);

  int mblk = (N_NODES + 127) / 128;  // 782
  // ---- t1 = bf16(x @ W1) ----
  gemm_mfma_kernel<1, 1, NFEAT, NHID><<<dim3(mblk, 1), 256, 0, stream>>>(
      x, (const __bf16*)W1t, nullptr, t1u, N_NODES);
  // ---- h = bf16(relu(A @ t1 + b1)) ----
  spmm_bf16_kernel<<<(N_NODES + 3) / 4, 256, 0, stream>>>(rowp, packedB, t1u, hu, b1, 1, N_NODES);
  // ---- t3 = bf16(A @ h) ----
  spmm_bf16_kernel<<<(N_NODES + 3) / 4, 256, 0, stream>>>(rowp, packedB, hu, t3u, nullptr, 0, N_NODES);
  // ---- out = t3 @ W2 + b2 (fp32 out) ----
  gemm_mfma_kernel<0, 0, NHID, NFEAT><<<dim3(mblk, 2), 256, 0, stream>>>(
      t3u, (const __bf16*)W2t, b2, outp, N_NODES);
  // ---- classifiers (one launch, both regions) ----
  cls_kernel<<<2048, 256, 0, stream>>>(t3u, Wc1, bc1, Wc2, bc2,
      outp + (size_t)N_NODES * NFEAT,
      outp + (size_t)N_NODES * NFEAT + (size_t)TEXT_CNT * NCLASS);
}

// Round 6
// 465.272 us; speedup vs baseline: 12.3507x; 1.0571x over previous
//
#include <hip/hip_runtime.h>

#define N_NODES  100000
#define N_EDGES  3200000
#define NFEAT    256
#define NHID     128
#define NCLASS   16
#define TEXT_CNT 50000

#define RPB      256                          // rows per bucket
#define NB       ((N_NODES + RPB - 1) / RPB)  // 391 buckets
#define CAP      16384                        // fixed bucket capacity (2^14)
#define S_EPT    8                            // edges/thread, scatter pass
#define NBLKS    ((N_EDGES + 256 * S_EPT - 1) / (256 * S_EPT))  // 1563

typedef unsigned int uint;
typedef __bf16 bf16x8 __attribute__((ext_vector_type(8)));
typedef __bf16 bf16x4 __attribute__((ext_vector_type(4)));
typedef float f32x4 __attribute__((ext_vector_type(4)));

__device__ inline uint bf16_rne(float f) {
  uint u = __float_as_uint(f);
  return (u + 0x7fffu + ((u >> 16) & 1u)) >> 16;
}
__device__ inline float bf_lo(uint u) { return __uint_as_float(u << 16); }
__device__ inline float bf_hi(uint u) { return __uint_as_float(u & 0xffff0000u); }

// ---------------- fused prep: W1t, W2t, Wc1/2, bc1/2, cursor init ----------------

__global__ __launch_bounds__(256) void prep_kernel(const float* __restrict__ W1,
                                                   const float* __restrict__ W2,
                                                   const float* __restrict__ b2,
                                                   const float* __restrict__ cW1,
                                                   const float* __restrict__ cb1,
                                                   const float* __restrict__ cW2,
                                                   const float* __restrict__ cb2,
                                                   unsigned short* __restrict__ W1t,
                                                   unsigned short* __restrict__ W2t,
                                                   float* __restrict__ Wc1, float* __restrict__ bc1,
                                                   float* __restrict__ Wc2, float* __restrict__ bc2,
                                                   int* __restrict__ gcursor) {
  int idx = blockIdx.x * 256 + threadIdx.x;
  if (idx < 32768) {                       // W1t[n][k] = bf16(W1[k][n]), K=256,N=128
    int n = idx >> 8, k = idx & 255;
    W1t[idx] = (unsigned short)bf16_rne(W1[(size_t)k * NHID + n]);
  } else if (idx < 65536) {                // W2t[n][k] = bf16(W2[k][n]), K=128,N=256
    int i2 = idx - 32768;
    int n = i2 >> 7, k = i2 & 127;
    W2t[i2] = (unsigned short)bf16_rne(W2[(size_t)k * NFEAT + n]);
  } else if (idx < 69632) {                // Wc = W2 @ cW
    int e = idx - 65536;
    int set = e >> 11;
    int e2 = e & 2047;
    int i = e2 >> 4, c = e2 & 15;
    const float* cw = set ? cW2 : cW1;
    float acc = 0.f;
    for (int k = 0; k < NFEAT; ++k)
      acc += W2[(size_t)i * NFEAT + k] * cw[k * NCLASS + c];
    (set ? Wc2 : Wc1)[e2] = acc;
    if (e < 32) {
      int s2 = e >> 4, c2 = e & 15;
      const float* cwb = s2 ? cW2 : cW1;
      float b = (s2 ? cb2 : cb1)[c2];
      for (int k = 0; k < NFEAT; ++k) b += b2[k] * cwb[k * NCLASS + c2];
      (s2 ? bc2 : bc1)[c2] = b;
    }
  } else if (idx < 69632 + NB) {           // gcursor[b] = b*CAP
    int b = idx - 69632;
    gcursor[b] = b * CAP;
  }
}

// ---------------- scatter body: edges -> fixed-cap bucket-grouped packed ----------------
// packedA[p] = { (rowlocal<<17) | col , float_bits(val) }

__device__ __forceinline__ void scatter_body(int bx, const int* __restrict__ rows,
                                             const int* __restrict__ cols,
                                             const float* __restrict__ vals,
                                             int* __restrict__ gcursor,
                                             int2* __restrict__ packed, int E) {
  __shared__ int hist[NB];
  __shared__ int cur[NB];
  for (int i = threadIdx.x; i < NB; i += 256) hist[i] = 0;
  __syncthreads();
  int base = bx * (256 * S_EPT);
#pragma unroll
  for (int i = 0; i < S_EPT; ++i) {
    int e = base + i * 256 + threadIdx.x;
    if (e < E) atomicAdd(&hist[rows[e] >> 8], 1);
  }
  __syncthreads();
  for (int i = threadIdx.x; i < NB; i += 256) {
    int h = hist[i];
    cur[i] = h ? atomicAdd(&gcursor[i], h) : 0;
  }
  __syncthreads();
#pragma unroll
  for (int i = 0; i < S_EPT; ++i) {
    int e = base + i * 256 + threadIdx.x;
    if (e < E) {
      int r = rows[e];
      int b = r >> 8;
      int p = atomicAdd(&cur[b], 1);
      if (p < ((b + 1) << 14))   // capacity guard
        packed[p] = make_int2(((r & 255) << 17) | cols[e], __float_as_int(vals[e]));
    }
  }
}

// ---------------- bf16 MFMA GEMM body: C[M,N] = A[M,K] @ Bt^T (+bias) ----------------
// 128x128 tile, BK=32, 256 threads = 4 waves (2x2), 4x4 16x16x32 frags/wave.

template <int A_FP32, int OUT_BF16, int K, int N>
__device__ __forceinline__ void gemm_body(int bx, int by, const void* __restrict__ Aptr,
                                          const __bf16* __restrict__ Bt,
                                          const float* __restrict__ bias,
                                          void* __restrict__ Cptr, int M) {
  __shared__ __bf16 As[128 * 40];
  __shared__ __bf16 Bs[128 * 40];
  int tid = threadIdx.x;
  int lane = tid & 63;
  int w = tid >> 6;
  int wr = w >> 1, wc = w & 1;
  int brow = bx * 128;
  int bcol = by * 128;
  int r16 = lane & 15, kb = lane >> 4;

  f32x4 acc[4][4];
#pragma unroll
  for (int m = 0; m < 4; ++m)
#pragma unroll
    for (int n = 0; n < 4; ++n) acc[m][n] = (f32x4){0.f, 0.f, 0.f, 0.f};

  for (int k0 = 0; k0 < K; k0 += 32) {
    if (A_FP32) {
      const float* A = (const float*)Aptr;
#pragma unroll
      for (int i = 0; i < 4; ++i) {
        int idx = tid + i * 256;
        int row = idx >> 3;
        int kq = (idx & 7) << 2;
        int gr = brow + row;
        float4 v = make_float4(0.f, 0.f, 0.f, 0.f);
        if (gr < M) v = *(const float4*)&A[(size_t)gr * K + k0 + kq];
        bf16x4 o;
        o[0] = (__bf16)v.x; o[1] = (__bf16)v.y; o[2] = (__bf16)v.z; o[3] = (__bf16)v.w;
        *(bf16x4*)&As[row * 40 + kq] = o;
      }
    } else {
      const __bf16* A = (const __bf16*)Aptr;
#pragma unroll
      for (int i = 0; i < 2; ++i) {
        int idx = tid + i * 256;
        int row = idx >> 2;
        int kq = (idx & 3) << 3;
        int gr = brow + row;
        bf16x8 v = {};
        if (gr < M) v = *(const bf16x8*)&A[(size_t)gr * K + k0 + kq];
        *(bf16x8*)&As[row * 40 + kq] = v;
      }
    }
#pragma unroll
    for (int i = 0; i < 2; ++i) {
      int idx = tid + i * 256;
      int col = idx >> 2;
      int kq = (idx & 3) << 3;
      bf16x8 v = *(const bf16x8*)&Bt[(size_t)(bcol + col) * K + k0 + kq];
      *(bf16x8*)&Bs[col * 40 + kq] = v;
    }
    __syncthreads();

    bf16x8 a[4], b[4];
#pragma unroll
    for (int m = 0; m < 4; ++m)
      a[m] = *(bf16x8*)&As[(wr * 64 + m * 16 + r16) * 40 + kb * 8];
#pragma unroll
    for (int n = 0; n < 4; ++n)
      b[n] = *(bf16x8*)&Bs[(wc * 64 + n * 16 + r16) * 40 + kb * 8];
#pragma unroll
    for (int m = 0; m < 4; ++m)
#pragma unroll
      for (int n = 0; n < 4; ++n)
        acc[m][n] = __builtin_amdgcn_mfma_f32_16x16x32_bf16(a[m], b[n], acc[m][n], 0, 0, 0);
    __syncthreads();
  }

  int crow0 = brow + wr * 64;
  int ccol0 = bcol + wc * 64;
#pragma unroll
  for (int n = 0; n < 4; ++n) {
    int col = ccol0 + n * 16 + r16;
    float bv = bias ? bias[col] : 0.f;
#pragma unroll
    for (int m = 0; m < 4; ++m) {
#pragma unroll
      for (int r = 0; r < 4; ++r) {
        int row = crow0 + m * 16 + kb * 4 + r;
        if (row < M) {
          float val = acc[m][n][r] + bv;
          if (OUT_BF16)
            ((unsigned short*)Cptr)[(size_t)row * N + col] = (unsigned short)bf16_rne(val);
          else
            ((float*)Cptr)[(size_t)row * N + col] = val;
        }
      }
    }
  }
}

// ---------------- fused: scatter (blocks [0,NBLKS)) + gemm1 (blocks [NBLKS, NBLKS+782)) ----------------

__global__ __launch_bounds__(256) void fused_scatter_gemm1_kernel(
    const int* __restrict__ rows, const int* __restrict__ cols, const float* __restrict__ vals,
    int* __restrict__ gcursor, int2* __restrict__ packedA, int E,
    const float* __restrict__ x, const __bf16* __restrict__ W1t, uint* __restrict__ t1u, int M) {
  if (blockIdx.x < NBLKS)
    scatter_body(blockIdx.x, rows, cols, vals, gcursor, packedA, E);
  else
    gemm_body<1, 1, NFEAT, NHID>(blockIdx.x - NBLKS, 0, x, W1t, nullptr, t1u, M);
}

// ---------------- scan bucket counts (from cursors) -> global CSR bases ----------------

__global__ __launch_bounds__(512) void bucket_scan_kernel(const int* __restrict__ gcursor,
                                                          int* __restrict__ bbase) {
  __shared__ int s[512];
  int t = threadIdx.x;
  int v = (t < NB) ? (gcursor[t] - t * CAP) : 0;
  s[t] = v;
  __syncthreads();
  for (int off = 1; off < 512; off <<= 1) {
    int u = (t >= off) ? s[t - off] : 0;
    __syncthreads();
    s[t] += u;
    __syncthreads();
  }
  if (t < NB) bbase[t] = s[t] - v;
  if (t == 0) bbase[NB] = N_EDGES;
}

// ---------------- per-bucket CSR finalize (512 threads) ----------------
// packedB[p] = { col<<8 (byte offset of feature row), float_bits(val) }

__global__ __launch_bounds__(512) void csr_finalize_kernel(const int* __restrict__ bbase,
                                                           const int2* __restrict__ packed_in,
                                                           int2* __restrict__ packed_out,
                                                           int* __restrict__ row_ptr) {
  __shared__ int hist[RPB];
  __shared__ int cur[RPB];
  int b = blockIdx.x;
  int s0 = b * CAP;
  int gout = bbase[b];
  int cnt = bbase[b + 1] - gout;
  int end = s0 + cnt;
  int t = threadIdx.x;
  if (t < RPB) hist[t] = 0;
  __syncthreads();
  {
    int i = s0 + t;
    for (; i + 1536 < end; i += 2048) {
      int2 a0 = packed_in[i], a1 = packed_in[i + 512];
      int2 a2 = packed_in[i + 1024], a3 = packed_in[i + 1536];
      atomicAdd(&hist[a0.x >> 17], 1);
      atomicAdd(&hist[a1.x >> 17], 1);
      atomicAdd(&hist[a2.x >> 17], 1);
      atomicAdd(&hist[a3.x >> 17], 1);
    }
    for (; i < end; i += 512) atomicAdd(&hist[packed_in[i].x >> 17], 1);
  }
  __syncthreads();
  int v = (t < RPB) ? hist[t] : 0;
  if (t < RPB) cur[t] = v;
  __syncthreads();
  for (int off = 1; off < RPB; off <<= 1) {
    int u = (t >= off && t < RPB) ? cur[t - off] : 0;
    __syncthreads();
    if (t < RPB) cur[t] += u;
    __syncthreads();
  }
  if (t < RPB) {
    int rbase = gout + cur[t] - v;
    int row = b * RPB + t;
    if (row < N_NODES) row_ptr[row] = rbase;
    cur[t] = rbase;
  }
  if (b == 0 && t == 0) row_ptr[N_NODES] = N_EDGES;
  __syncthreads();
  {
    int i = s0 + t;
    for (; i + 1536 < end; i += 2048) {
      int2 a0 = packed_in[i], a1 = packed_in[i + 512];
      int2 a2 = packed_in[i + 1024], a3 = packed_in[i + 1536];
      int p0 = atomicAdd(&cur[a0.x >> 17], 1);
      int p1 = atomicAdd(&cur[a1.x >> 17], 1);
      int p2 = atomicAdd(&cur[a2.x >> 17], 1);
      int p3 = atomicAdd(&cur[a3.x >> 17], 1);
      packed_out[p0] = make_int2((a0.x & 0x1FFFF) << 8, a0.y);
      packed_out[p1] = make_int2((a1.x & 0x1FFFF) << 8, a1.y);
      packed_out[p2] = make_int2((a2.x & 0x1FFFF) << 8, a2.y);
      packed_out[p3] = make_int2((a3.x & 0x1FFFF) << 8, a3.y);
    }
    for (; i < end; i += 512) {
      int2 pk = packed_in[i];
      int p = atomicAdd(&cur[pk.x >> 17], 1);
      packed_out[p] = make_int2((pk.x & 0x1FFFF) << 8, pk.y);
    }
  }
}

// ---------------- CSR SpMM over bf16 features, wave per row, 8B/lane pair-loads ----------------
// Lane L: half = L>>5 covers edge pair-member, l32 = L&31 covers features 4*l32..4*l32+3.

__global__ __launch_bounds__(256) void spmm_bf16_kernel(const int* __restrict__ row_ptr,
                                                        const int2* __restrict__ packed,
                                                        const uint* __restrict__ src,   // [n][64] dwords
                                                        uint* __restrict__ dst,         // [n][64] dwords
                                                        const float* __restrict__ bias,
                                                        int relu, int nrows) {
  int tid = threadIdx.x;
  int lane = tid & 63;
  int half = lane >> 5;
  int l32 = lane & 31;
  int row = blockIdx.x * 4 + (tid >> 6);
  if (row >= nrows) return;
  int s = row_ptr[row];
  int e = row_ptr[row + 1];
  const char* srcb = (const char*)src + (l32 << 3);
  float a0 = 0.f, a1 = 0.f, a2 = 0.f, a3 = 0.f;
  int i = s;
  // 16 edges: 8 pair-loads in flight
  for (; i + 16 <= e; i += 16) {
    int2 m0 = packed[i + 0 + half], m1 = packed[i + 2 + half];
    int2 m2 = packed[i + 4 + half], m3 = packed[i + 6 + half];
    int2 m4 = packed[i + 8 + half], m5 = packed[i + 10 + half];
    int2 m6 = packed[i + 12 + half], m7 = packed[i + 14 + half];
    uint2 u0 = *(const uint2*)(srcb + (uint)m0.x);
    uint2 u1 = *(const uint2*)(srcb + (uint)m1.x);
    uint2 u2 = *(const uint2*)(srcb + (uint)m2.x);
    uint2 u3 = *(const uint2*)(srcb + (uint)m3.x);
    uint2 u4 = *(const uint2*)(srcb + (uint)m4.x);
    uint2 u5 = *(const uint2*)(srcb + (uint)m5.x);
    uint2 u6 = *(const uint2*)(srcb + (uint)m6.x);
    uint2 u7 = *(const uint2*)(srcb + (uint)m7.x);
    float v0 = __int_as_float(m0.y), v1 = __int_as_float(m1.y);
    float v2 = __int_as_float(m2.y), v3 = __int_as_float(m3.y);
    float v4 = __int_as_float(m4.y), v5 = __int_as_float(m5.y);
    float v6 = __int_as_float(m6.y), v7 = __int_as_float(m7.y);
    a0 += v0 * bf_lo(u0.x); a1 += v0 * bf_hi(u0.x); a2 += v0 * bf_lo(u0.y); a3 += v0 * bf_hi(u0.y);
    a0 += v1 * bf_lo(u1.x); a1 += v1 * bf_hi(u1.x); a2 += v1 * bf_lo(u1.y); a3 += v1 * bf_hi(u1.y);
    a0 += v2 * bf_lo(u2.x); a1 += v2 * bf_hi(u2.x); a2 += v2 * bf_lo(u2.y); a3 += v2 * bf_hi(u2.y);
    a0 += v3 * bf_lo(u3.x); a1 += v3 * bf_hi(u3.x); a2 += v3 * bf_lo(u3.y); a3 += v3 * bf_hi(u3.y);
    a0 += v4 * bf_lo(u4.x); a1 += v4 * bf_hi(u4.x); a2 += v4 * bf_lo(u4.y); a3 += v4 * bf_hi(u4.y);
    a0 += v5 * bf_lo(u5.x); a1 += v5 * bf_hi(u5.x); a2 += v5 * bf_lo(u5.y); a3 += v5 * bf_hi(u5.y);
    a0 += v6 * bf_lo(u6.x); a1 += v6 * bf_hi(u6.x); a2 += v6 * bf_lo(u6.y); a3 += v6 * bf_hi(u6.y);
    a0 += v7 * bf_lo(u7.x); a1 += v7 * bf_hi(u7.x); a2 += v7 * bf_lo(u7.y); a3 += v7 * bf_hi(u7.y);
  }
  // 8 edges
  for (; i + 8 <= e; i += 8) {
    int2 m0 = packed[i + 0 + half], m1 = packed[i + 2 + half];
    int2 m2 = packed[i + 4 + half], m3 = packed[i + 6 + half];
    uint2 u0 = *(const uint2*)(srcb + (uint)m0.x);
    uint2 u1 = *(const uint2*)(srcb + (uint)m1.x);
    uint2 u2 = *(const uint2*)(srcb + (uint)m2.x);
    uint2 u3 = *(const uint2*)(srcb + (uint)m3.x);
    float v0 = __int_as_float(m0.y), v1 = __int_as_float(m1.y);
    float v2 = __int_as_float(m2.y), v3 = __int_as_float(m3.y);
    a0 += v0 * bf_lo(u0.x); a1 += v0 * bf_hi(u0.x); a2 += v0 * bf_lo(u0.y); a3 += v0 * bf_hi(u0.y);
    a0 += v1 * bf_lo(u1.x); a1 += v1 * bf_hi(u1.x); a2 += v1 * bf_lo(u1.y); a3 += v1 * bf_hi(u1.y);
    a0 += v2 * bf_lo(u2.x); a1 += v2 * bf_hi(u2.x); a2 += v2 * bf_lo(u2.y); a3 += v2 * bf_hi(u2.y);
    a0 += v3 * bf_lo(u3.x); a1 += v3 * bf_hi(u3.x); a2 += v3 * bf_lo(u3.y); a3 += v3 * bf_hi(u3.y);
  }
  // 4 edges
  for (; i + 4 <= e; i += 4) {
    int2 m0 = packed[i + 0 + half], m1 = packed[i + 2 + half];
    uint2 u0 = *(const uint2*)(srcb + (uint)m0.x);
    uint2 u1 = *(const uint2*)(srcb + (uint)m1.x);
    float v0 = __int_as_float(m0.y), v1 = __int_as_float(m1.y);
    a0 += v0 * bf_lo(u0.x); a1 += v0 * bf_hi(u0.x); a2 += v0 * bf_lo(u0.y); a3 += v0 * bf_hi(u0.y);
    a0 += v1 * bf_lo(u1.x); a1 += v1 * bf_hi(u1.x); a2 += v1 * bf_lo(u1.y); a3 += v1 * bf_hi(u1.y);
  }
  // 1-2 edges (guarded pair)
  for (; i < e; i += 2) {
    int ee = i + half;
    int ok = ee < e;
    int2 m = packed[ok ? ee : (e - 1)];
    uint2 u = *(const uint2*)(srcb + (uint)m.x);
    float v = ok ? __int_as_float(m.y) : 0.f;
    a0 += v * bf_lo(u.x); a1 += v * bf_hi(u.x); a2 += v * bf_lo(u.y); a3 += v * bf_hi(u.y);
  }
  // cross-half reduce
  a0 += __shfl_xor(a0, 32); a1 += __shfl_xor(a1, 32);
  a2 += __shfl_xor(a2, 32); a3 += __shfl_xor(a3, 32);
  if (half == 0) {
    if (bias) {
      a0 += bias[4 * l32 + 0]; a1 += bias[4 * l32 + 1];
      a2 += bias[4 * l32 + 2]; a3 += bias[4 * l32 + 3];
    }
    if (relu) {
      a0 = fmaxf(a0, 0.f); a1 = fmaxf(a1, 0.f);
      a2 = fmaxf(a2, 0.f); a3 = fmaxf(a3, 0.f);
    }
    uint2 o;
    o.x = bf16_rne(a0) | (bf16_rne(a1) << 16);
    o.y = bf16_rne(a2) | (bf16_rne(a3) << 16);
    *(uint2*)&dst[(size_t)row * 64 + l32 * 2] = o;
  }
}

// ---------------- standalone GEMM kernel (for gemm2) ----------------

template <int A_FP32, int OUT_BF16, int K, int N>
__global__ __launch_bounds__(256) void gemm_mfma_kernel(const void* __restrict__ Aptr,
                                                        const __bf16* __restrict__ Bt,
                                                        const float* __restrict__ bias,
                                                        void* __restrict__ Cptr, int M) {
  gemm_body<A_FP32, OUT_BF16, K, N>(blockIdx.x, blockIdx.y, Aptr, Bt, bias, Cptr, M);
}

// ---------------- classifier (both regions in one launch) ----------------

__global__ __launch_bounds__(256) void cls_kernel(const uint* __restrict__ t3,
                                                  const float* __restrict__ Wc1,
                                                  const float* __restrict__ bc1,
                                                  const float* __restrict__ Wc2,
                                                  const float* __restrict__ bc2,
                                                  float* __restrict__ out1,
                                                  float* __restrict__ out2) {
  int half = gridDim.x >> 1;
  int region = blockIdx.x >= half;
  int bid = region ? blockIdx.x - half : blockIdx.x;
  const float* Wc = region ? Wc2 : Wc1;
  const float* bc = region ? bc2 : bc1;
  float* outp = region ? out2 : out1;
  int row0 = region ? TEXT_CNT : 0;
  int nrows = region ? (N_NODES - TEXT_CNT) : TEXT_CNT;

  int lane = threadIdx.x & 63;
  int wav = bid * 4 + (threadIdx.x >> 6);
  int nw = half * 4;
  int c = lane & 15;
  int kg = lane >> 4;
  float w[32];
#pragma unroll
  for (int j = 0; j < 32; ++j) w[j] = Wc[(kg * 32 + j) * NCLASS + c];
  float bcv = bc[c];
  for (int r = wav; r < nrows; r += nw) {
    const uint4* rp = (const uint4*)&t3[(size_t)(row0 + r) * 64 + kg * 16];
    float acc = 0.f;
#pragma unroll
    for (int q = 0; q < 4; ++q) {
      uint4 u = rp[q];
      acc += bf_lo(u.x) * w[q * 8 + 0] + bf_hi(u.x) * w[q * 8 + 1]
           + bf_lo(u.y) * w[q * 8 + 2] + bf_hi(u.y) * w[q * 8 + 3]
           + bf_lo(u.z) * w[q * 8 + 4] + bf_hi(u.z) * w[q * 8 + 5]
           + bf_lo(u.w) * w[q * 8 + 6] + bf_hi(u.w) * w[q * 8 + 7];
    }
    acc += __shfl_xor(acc, 16);
    acc += __shfl_xor(acc, 32);
    if (lane < 16) outp[(size_t)r * NCLASS + lane] = acc + bcv;
  }
}

// ---------------- launch ----------------

extern "C" void kernel_launch(void* const* d_in, const int* in_sizes, int n_in,
                              void* d_out, int out_size, void* d_ws, size_t ws_size,
                              hipStream_t stream) {
  const float* x     = (const float*)d_in[0];
  const int*   arows = (const int*)d_in[1];
  const int*   acols = (const int*)d_in[2];
  const float* avals = (const float*)d_in[3];
  const float* W1    = (const float*)d_in[4];
  const float* b1    = (const float*)d_in[5];
  const float* W2    = (const float*)d_in[6];
  const float* b2    = (const float*)d_in[7];
  const float* cW1   = (const float*)d_in[8];
  const float* cb1   = (const float*)d_in[9];
  const float* cW2   = (const float*)d_in[10];
  const float* cb2   = (const float*)d_in[11];
  float* outp = (float*)d_out;

  char* ws = (char*)d_ws;
  size_t off = 0;
  auto alloc = [&](size_t bytes) -> void* {
    void* p = ws + off;
    off += (bytes + 255) & ~(size_t)255;
    return p;
  };
  uint*  t1u     = (uint*) alloc((size_t)N_NODES * 64 * 4);   // bf16 [N][128]
  uint*  hu      = (uint*) alloc((size_t)N_NODES * 64 * 4);   // bf16 [N][128]
  uint*  t3u     = (uint*) alloc((size_t)N_NODES * 64 * 4);   // bf16 [N][128]
  int2*  packedA = (int2*) alloc((size_t)NB * CAP * 8);       // fixed-cap buckets
  int2*  packedB = (int2*) alloc((size_t)N_EDGES * 8);        // row-grouped (CSR)
  int*   bbase   = (int*)  alloc((size_t)(NB + 1) * 4);
  int*   gcursor = (int*)  alloc((size_t)NB * 4);
  int*   rowp    = (int*)  alloc((size_t)(N_NODES + 1) * 4);
  unsigned short* W1t = (unsigned short*)alloc((size_t)NHID * NFEAT * 2);  // [128][256]
  unsigned short* W2t = (unsigned short*)alloc((size_t)NFEAT * NHID * 2);  // [256][128]
  float* Wc1     = (float*)alloc(NHID * NCLASS * 4);
  float* Wc2     = (float*)alloc(NHID * NCLASS * 4);
  float* bc1     = (float*)alloc(64);
  float* bc2     = (float*)alloc(64);

  // ---- 1. fused prep (weights + cursors) ----
  prep_kernel<<<(69632 + NB + 255) / 256, 256, 0, stream>>>(
      W1, W2, b2, cW1, cb1, cW2, cb2, W1t, W2t, Wc1, bc1, Wc2, bc2, gcursor);

  // ---- 2. fused scatter + t1 = bf16(x @ W1) ----
  int mblk = (N_NODES + 127) / 128;  // 782
  fused_scatter_gemm1_kernel<<<NBLKS + mblk, 256, 0, stream>>>(
      arows, acols, avals, gcursor, packedA, N_EDGES,
      x, (const __bf16*)W1t, t1u, N_NODES);

  // ---- 3-4. scan + finalize ----
  bucket_scan_kernel<<<1, 512, 0, stream>>>(gcursor, bbase);
  csr_finalize_kernel<<<NB, 512, 0, stream>>>(bbase, packedA, packedB, rowp);

  // ---- 5. h = bf16(relu(A @ t1 + b1)) ----
  spmm_bf16_kernel<<<(N_NODES + 3) / 4, 256, 0, stream>>>(rowp, packedB, t1u, hu, b1, 1, N_NODES);
  // ---- 6. t3 = bf16(A @ h) ----
  spmm_bf16_kernel<<<(N_NODES + 3) / 4, 256, 0, stream>>>(rowp, packedB, hu, t3u, nullptr, 0, N_NODES);
  // ---- 7. out = t3 @ W2 + b2 (fp32 out) ----
  gemm_mfma_kernel<0, 0, NHID, NFEAT><<<dim3(mblk, 2), 256, 0, stream>>>(
      t3u, (const __bf16*)W2t, b2, outp, N_NODES);
  // ---- 8. classifiers ----
  cls_kernel<<<2048, 256, 0, stream>>>(t3u, Wc1, bc1, Wc2, bc2,
      outp + (size_t)N_NODES * NFEAT,
      outp + (size_t)N_NODES * NFEAT + (size_t)TEXT_CNT * NCLASS);
}